// Round 7
// baseline (495.542 us; speedup 1.0000x reference)
//
#include <hip/hip_runtime.h>
#include <math.h>

#define HEADS 4
#define CH 128
#define HC 512
#define GRAPHS 128
#define OUT_DIM 8

typedef unsigned short u16;
typedef unsigned int u32;
typedef short short8 __attribute__((ext_vector_type(8)));
typedef float f32x4 __attribute__((ext_vector_type(4)));

__device__ inline u16 f2b(float f) {
  u32 u = __float_as_uint(f);
  u32 r = u + 0x7FFFu + ((u >> 16) & 1u);
  return (u16)(r >> 16);
}
__device__ inline float blo(u32 d) { return __uint_as_float(d << 16); }
__device__ inline float bhi(u32 d) { return __uint_as_float(d & 0xffff0000u); }
__device__ inline float lrelu(float v) { return v > 0.f ? v : 0.2f * v; }

// ---------------- CSR build ----------------
__global__ void k_count(const int* __restrict__ ei, int* __restrict__ counts, int E, int N) {
  int i = blockIdx.x * blockDim.x + threadIdx.x;
  int total = E + N;
  if (i >= total) return;
  int dst = (i < E) ? ei[E + i] : (i - E);
  atomicAdd(&counts[dst], 1);
}

__global__ __launch_bounds__(256) void k_scanA(const int* __restrict__ counts,
                                               int* __restrict__ bsum, int N) {
  __shared__ int sh[256];
  int b = blockIdx.x, t = threadIdx.x, i = b * 256 + t;
  sh[t] = (i < N) ? counts[i] : 0;
  __syncthreads();
  for (int off = 128; off; off >>= 1) {
    if (t < off) sh[t] += sh[t + off];
    __syncthreads();
  }
  if (t == 0) bsum[b] = sh[0];
}

__global__ __launch_bounds__(1024) void k_scanB(const int* __restrict__ bsum,
                                                int* __restrict__ boff, int nb) {
  __shared__ int sh[1024];
  int t = threadIdx.x;
  sh[t] = (t < nb) ? bsum[t] : 0;
  __syncthreads();
  for (int off = 1; off < 1024; off <<= 1) {
    int v = sh[t];
    int u = (t >= off) ? sh[t - off] : 0;
    __syncthreads();
    sh[t] = v + u;
    __syncthreads();
  }
  if (t < nb) boff[t] = (t == 0) ? 0 : sh[t - 1];
}

__global__ __launch_bounds__(256) void k_scanC(const int* __restrict__ counts,
                                               const int* __restrict__ boff,
                                               int* __restrict__ indptr,
                                               int* __restrict__ cursor, int N) {
  __shared__ int sh[256];
  int b = blockIdx.x, t = threadIdx.x, i = b * 256 + t;
  int v = (i < N) ? counts[i] : 0;
  sh[t] = v;
  __syncthreads();
  for (int off = 1; off < 256; off <<= 1) {
    int a = sh[t];
    int u = (t >= off) ? sh[t - off] : 0;
    __syncthreads();
    sh[t] = a + u;
    __syncthreads();
  }
  if (i < N) {
    int excl = boff[b] + sh[t] - v;
    indptr[i] = excl;
    cursor[i] = excl;
    if (i == N - 1) indptr[N] = excl + v;
  }
}

__global__ void k_scatter(const int* __restrict__ ei, int* __restrict__ cursor,
                          int* __restrict__ srcs, int E, int N) {
  int i = blockIdx.x * blockDim.x + threadIdx.x;
  int total = E + N;
  if (i >= total) return;
  int src, dst;
  if (i < E) { src = ei[i]; dst = ei[E + i]; } else { src = i - E; dst = i - E; }
  int pos = atomicAdd(&cursor[dst], 1);
  srcs[pos] = src;
}

// ---------------- converters ----------------
// W [K][Nc] fp32 -> Wt [Nc][K] bf16 (transposed)
__global__ void k_wt(const float* __restrict__ W, u16* __restrict__ Wt, int K, int Nc) {
  int i = blockIdx.x * blockDim.x + threadIdx.x;
  if (i >= K * Nc) return;
  int n = i / K, k = i - n * K;
  Wt[i] = f2b(W[(size_t)k * Nc + n]);
}

// ws[k][o]: o in 0..3 = src heads, 4..7 = dst heads.  ws = W1_head @ att_head
__global__ __launch_bounds__(256) void k_ws(const float* __restrict__ W1,
                                            const float* __restrict__ as1,
                                            const float* __restrict__ ad1,
                                            float* __restrict__ ws) {
  int t = threadIdx.x;
  #pragma unroll
  for (int r = 0; r < 4; r++) {
    int idx = r * 256 + t;       // 0..1023
    int k = idx >> 3, o = idx & 7, h = o & 3;
    const float* av = ((o < 4) ? as1 : ad1) + h * CH;
    const float* wrow = W1 + (size_t)k * HC + h * CH;
    float s = 0.f;
    for (int c = 0; c < CH; c++) s += wrow[c] * av[c];
    ws[idx] = s;
  }
}

// ---------------- fused x->bf16 conversion + conv1 scores (wave per node) ----------------
__global__ void k_prep(const float* __restrict__ x, const float* __restrict__ ws,
                       u32* __restrict__ xb, float4* __restrict__ sa1,
                       float4* __restrict__ da1, int N) {
  int n = blockIdx.x * (blockDim.x >> 6) + (threadIdx.x >> 6);
  int lane = threadIdx.x & 63;
  if (n >= N) return;
  float2 v = ((const float2*)(x + (size_t)n * 128))[lane];
  xb[(size_t)n * 64 + lane] = (u32)f2b(v.x) | ((u32)f2b(v.y) << 16);
  const float* w0 = ws + (2 * lane) * 8;
  const float* w1 = ws + (2 * lane + 1) * 8;
  float p[8];
  #pragma unroll
  for (int o = 0; o < 8; o++) p[o] = v.x * w0[o] + v.y * w1[o];
  #pragma unroll
  for (int off = 32; off; off >>= 1)
    #pragma unroll
    for (int o = 0; o < 8; o++) p[o] += __shfl_xor(p[o], off);
  if (lane == 0) {
    sa1[n] = make_float4(p[0], p[1], p[2], p[3]);
    da1[n] = make_float4(p[4], p[5], p[6], p[7]);
  }
}

// ---------------- conv1 aggregation over x (bf16), 4 heads, HALF-WAVE PER NODE ----------------
// dsum accumulated from the broadcast weights (no cross-lane reduction needed).
__global__ __launch_bounds__(256) void k_aggx(
    const u32* __restrict__ xb, const int* __restrict__ indptr,
    const int* __restrict__ srcs, const float4* __restrict__ as1,
    const float4* __restrict__ ad1, u32* __restrict__ aggx, int N) {
  int t = threadIdx.x;
  int n = blockIdx.x * 8 + (t >> 5);
  if (n >= N) return;
  int hl = t & 31;
  int hbase = t & 32;          // base lane of my half within the wave
  int beg = indptr[n], end = indptr[n + 1];
  float4 ad = ad1[n];
  float ds0 = 0.f, ds1 = 0.f, ds2 = 0.f, ds3 = 0.f;
  float a00 = 0.f, a01 = 0.f, a02 = 0.f, a03 = 0.f;
  float a10 = 0.f, a11 = 0.f, a12 = 0.f, a13 = 0.f;
  float a20 = 0.f, a21 = 0.f, a22 = 0.f, a23 = 0.f;
  float a30 = 0.f, a31 = 0.f, a32 = 0.f, a33 = 0.f;

  for (int base = beg; base < end; base += 32) {
    int cnt = min(32, end - base);
    int sreg = 0;
    float w0 = 0.f, w1 = 0.f, w2 = 0.f, w3 = 0.f;
    if (hl < cnt) {
      sreg = srcs[base + hl];
      float4 a = as1[sreg];
      w0 = __expf(lrelu(a.x + ad.x));
      w1 = __expf(lrelu(a.y + ad.y));
      w2 = __expf(lrelu(a.z + ad.z));
      w3 = __expf(lrelu(a.w + ad.w));
    }
    int j = 0;
    for (; j + 4 <= cnt; j += 4) {
      int sA = __shfl(sreg, hbase + j),     sB = __shfl(sreg, hbase + j + 1);
      int sC = __shfl(sreg, hbase + j + 2), sD = __shfl(sreg, hbase + j + 3);
      uint2 dA = *(const uint2*)(xb + (size_t)sA * 64 + 2 * hl);
      uint2 dB = *(const uint2*)(xb + (size_t)sB * 64 + 2 * hl);
      uint2 dC = *(const uint2*)(xb + (size_t)sC * 64 + 2 * hl);
      uint2 dD = *(const uint2*)(xb + (size_t)sD * 64 + 2 * hl);
      float xA0 = blo(dA.x), xA1 = bhi(dA.x), xA2 = blo(dA.y), xA3 = bhi(dA.y);
      float xB0 = blo(dB.x), xB1 = bhi(dB.x), xB2 = blo(dB.y), xB3 = bhi(dB.y);
      float xC0 = blo(dC.x), xC1 = bhi(dC.x), xC2 = blo(dC.y), xC3 = bhi(dC.y);
      float xD0 = blo(dD.x), xD1 = bhi(dD.x), xD2 = blo(dD.y), xD3 = bhi(dD.y);
      float wA, wB, wC, wD;
      wA = __shfl(w0, hbase + j); wB = __shfl(w0, hbase + j + 1);
      wC = __shfl(w0, hbase + j + 2); wD = __shfl(w0, hbase + j + 3);
      ds0 += wA + wB + wC + wD;
      a00 += wA * xA0 + wB * xB0 + wC * xC0 + wD * xD0;
      a01 += wA * xA1 + wB * xB1 + wC * xC1 + wD * xD1;
      a02 += wA * xA2 + wB * xB2 + wC * xC2 + wD * xD2;
      a03 += wA * xA3 + wB * xB3 + wC * xC3 + wD * xD3;
      wA = __shfl(w1, hbase + j); wB = __shfl(w1, hbase + j + 1);
      wC = __shfl(w1, hbase + j + 2); wD = __shfl(w1, hbase + j + 3);
      ds1 += wA + wB + wC + wD;
      a10 += wA * xA0 + wB * xB0 + wC * xC0 + wD * xD0;
      a11 += wA * xA1 + wB * xB1 + wC * xC1 + wD * xD1;
      a12 += wA * xA2 + wB * xB2 + wC * xC2 + wD * xD2;
      a13 += wA * xA3 + wB * xB3 + wC * xC3 + wD * xD3;
      wA = __shfl(w2, hbase + j); wB = __shfl(w2, hbase + j + 1);
      wC = __shfl(w2, hbase + j + 2); wD = __shfl(w2, hbase + j + 3);
      ds2 += wA + wB + wC + wD;
      a20 += wA * xA0 + wB * xB0 + wC * xC0 + wD * xD0;
      a21 += wA * xA1 + wB * xB1 + wC * xC1 + wD * xD1;
      a22 += wA * xA2 + wB * xB2 + wC * xC2 + wD * xD2;
      a23 += wA * xA3 + wB * xB3 + wC * xC3 + wD * xD3;
      wA = __shfl(w3, hbase + j); wB = __shfl(w3, hbase + j + 1);
      wC = __shfl(w3, hbase + j + 2); wD = __shfl(w3, hbase + j + 3);
      ds3 += wA + wB + wC + wD;
      a30 += wA * xA0 + wB * xB0 + wC * xC0 + wD * xD0;
      a31 += wA * xA1 + wB * xB1 + wC * xC1 + wD * xD1;
      a32 += wA * xA2 + wB * xB2 + wC * xC2 + wD * xD2;
      a33 += wA * xA3 + wB * xB3 + wC * xC3 + wD * xD3;
    }
    for (; j < cnt; j++) {
      int sA = __shfl(sreg, hbase + j);
      uint2 dA = *(const uint2*)(xb + (size_t)sA * 64 + 2 * hl);
      float xA0 = blo(dA.x), xA1 = bhi(dA.x), xA2 = blo(dA.y), xA3 = bhi(dA.y);
      float wA;
      wA = __shfl(w0, hbase + j); ds0 += wA;
      a00 += wA * xA0; a01 += wA * xA1; a02 += wA * xA2; a03 += wA * xA3;
      wA = __shfl(w1, hbase + j); ds1 += wA;
      a10 += wA * xA0; a11 += wA * xA1; a12 += wA * xA2; a13 += wA * xA3;
      wA = __shfl(w2, hbase + j); ds2 += wA;
      a20 += wA * xA0; a21 += wA * xA1; a22 += wA * xA2; a23 += wA * xA3;
      wA = __shfl(w3, hbase + j); ds3 += wA;
      a30 += wA * xA0; a31 += wA * xA1; a32 += wA * xA2; a33 += wA * xA3;
    }
  }
  float i0 = 1.f / (ds0 + 1e-16f), i1 = 1.f / (ds1 + 1e-16f);
  float i2 = 1.f / (ds2 + 1e-16f), i3 = 1.f / (ds3 + 1e-16f);
  u32* orow = aggx + (size_t)n * 256;
  *(uint2*)(orow + 2 * hl) =
      make_uint2((u32)f2b(a00 * i0) | ((u32)f2b(a01 * i0) << 16),
                 (u32)f2b(a02 * i0) | ((u32)f2b(a03 * i0) << 16));
  *(uint2*)(orow + 64 + 2 * hl) =
      make_uint2((u32)f2b(a10 * i1) | ((u32)f2b(a11 * i1) << 16),
                 (u32)f2b(a12 * i1) | ((u32)f2b(a13 * i1) << 16));
  *(uint2*)(orow + 128 + 2 * hl) =
      make_uint2((u32)f2b(a20 * i2) | ((u32)f2b(a21 * i2) << 16),
                 (u32)f2b(a22 * i2) | ((u32)f2b(a23 * i2) << 16));
  *(uint2*)(orow + 192 + 2 * hl) =
      make_uint2((u32)f2b(a30 * i3) | ((u32)f2b(a31 * i3) << 16),
                 (u32)f2b(a32 * i3) | ((u32)f2b(a33 * i3) << 16));
}

// ---------------- per-head GEMM: raw1[:, hC:(h+1)C] = aggx[:,h,:] @ W1[:,hC:(h+1)C] + b1 ----------------
__global__ __launch_bounds__(256) void k_gemm_head(
    const u16* __restrict__ A,    // aggx [M][512]
    const u16* __restrict__ Bt,   // W1t  [512][128]
    const float* __restrict__ bias,
    u16* __restrict__ C,          // raw1 [M][512]
    int M) {
  __shared__ u16 As[128 * 64];
  __shared__ u16 Bs[128 * 64];
  int t = threadIdx.x;
  int lane = t & 63, wid = t >> 6;
  int wr = wid >> 1, wc = wid & 1;
  int r0 = blockIdx.x * 128;
  int hh = blockIdx.y;
  const u16* Ah = A + hh * 128;
  const u16* Bh = Bt + (size_t)hh * 128 * 128;
  int lr = lane & 15, lk = lane >> 4;
  f32x4 acc[4][4] = {};
  for (int kt = 0; kt < 128; kt += 64) {
    #pragma unroll
    for (int it = 0; it < 4; it++) {
      int q = wid * 4096 + it * 1024 + lane * 16;
      int row = q >> 7;
      int soff = ((q >> 4) & 7) ^ (row & 7);
      {
        int gr = r0 + row; if (gr >= M) gr = M - 1;
        const u16* gp = Ah + (size_t)gr * 512 + kt + soff * 8;
        __builtin_amdgcn_global_load_lds(
            (const __attribute__((address_space(1))) void*)gp,
            (__attribute__((address_space(3))) void*)((char*)As + wid * 4096 + it * 1024),
            16, 0, 0);
      }
      {
        const u16* gp = Bh + (size_t)row * 128 + kt + soff * 8;
        __builtin_amdgcn_global_load_lds(
            (const __attribute__((address_space(1))) void*)gp,
            (__attribute__((address_space(3))) void*)((char*)Bs + wid * 4096 + it * 1024),
            16, 0, 0);
      }
    }
    __syncthreads();
    const char* Ab = (const char*)As;
    const char* Bb = (const char*)Bs;
    #pragma unroll
    for (int kk = 0; kk < 2; kk++) {
      short8 a[4], b[4];
      #pragma unroll
      for (int m = 0; m < 4; m++) {
        int row = wr * 64 + m * 16 + lr;
        int off = (row << 7) + kk * 64 + lk * 16;
        off ^= (row & 7) << 4;
        a[m] = *(const short8*)(Ab + off);
      }
      #pragma unroll
      for (int nn = 0; nn < 4; nn++) {
        int row = wc * 64 + nn * 16 + lr;
        int off = (row << 7) + kk * 64 + lk * 16;
        off ^= (row & 7) << 4;
        b[nn] = *(const short8*)(Bb + off);
      }
      #pragma unroll
      for (int m = 0; m < 4; m++)
        #pragma unroll
        for (int nn = 0; nn < 4; nn++)
          acc[m][nn] = __builtin_amdgcn_mfma_f32_16x16x32_bf16(a[m], b[nn], acc[m][nn], 0, 0, 0);
    }
    __syncthreads();
  }
  #pragma unroll
  for (int m = 0; m < 4; m++)
    #pragma unroll
    for (int nn = 0; nn < 4; nn++)
      #pragma unroll
      for (int r = 0; r < 4; r++) {
        int row = r0 + wr * 64 + m * 16 + lk * 4 + r;
        if (row < M) {
          int gcol = hh * 128 + wc * 64 + nn * 16 + lr;
          C[(size_t)row * 512 + gcol] = f2b(acc[m][nn][r] + bias[gcol]);
        }
      }
}

// ---------------- LN+ReLU over 512 channels (bf16 in/out) ----------------
__global__ __launch_bounds__(256) void k_ln512(const u16* __restrict__ raw,
                                               const float* __restrict__ gam,
                                               const float* __restrict__ bet,
                                               u16* __restrict__ out, int N) {
  int n = blockIdx.x * 4 + (threadIdx.x >> 6);
  int lane = threadIdx.x & 63;
  if (n >= N) return;
  const uint4* r = (const uint4*)(raw + (size_t)n * 512);
  uint4 q = r[lane];
  float v[8];
  v[0] = blo(q.x); v[1] = bhi(q.x); v[2] = blo(q.y); v[3] = bhi(q.y);
  v[4] = blo(q.z); v[5] = bhi(q.z); v[6] = blo(q.w); v[7] = bhi(q.w);
  float s1 = 0.f, s2 = 0.f;
  #pragma unroll
  for (int j = 0; j < 8; j++) { s1 += v[j]; s2 += v[j] * v[j]; }
  #pragma unroll
  for (int off = 32; off; off >>= 1) {
    s1 += __shfl_xor(s1, off);
    s2 += __shfl_xor(s2, off);
  }
  float mean = s1 * (1.f / 512.f);
  float var = s2 * (1.f / 512.f) - mean * mean;
  float rs = rsqrtf(var + 1e-5f);
  u32 o[4];
  #pragma unroll
  for (int j = 0; j < 4; j++) {
    int ch = lane * 8 + 2 * j;
    float y0 = fmaxf((v[2 * j] - mean) * rs * gam[ch] + bet[ch], 0.f);
    float y1 = fmaxf((v[2 * j + 1] - mean) * rs * gam[ch + 1] + bet[ch + 1], 0.f);
    o[j] = (u32)f2b(y0) | ((u32)f2b(y1) << 16);
  }
  ((uint4*)(out + (size_t)n * 512))[lane] = make_uint4(o[0], o[1], o[2], o[3]);
}

// ---------------- bf16 MFMA GEMM (conv2): C[M][128] = A[M][512] * Bt[128][512]^T ----------------
__global__ __launch_bounds__(256) void k_gemm_bf16(
    const u16* __restrict__ A, const u16* __restrict__ Bt,
    u16* __restrict__ C, int M, int Nc, int K) {
  __shared__ u16 As[128 * 64];
  __shared__ u16 Bs[128 * 64];
  int t = threadIdx.x;
  int lane = t & 63, wid = t >> 6;
  int wr = wid >> 1, wc = wid & 1;
  int r0 = blockIdx.x * 128, c0 = blockIdx.y * 128;
  int lr = lane & 15, lk = lane >> 4;
  f32x4 acc[4][4] = {};
  for (int kt = 0; kt < K; kt += 64) {
    #pragma unroll
    for (int it = 0; it < 4; it++) {
      int q = wid * 4096 + it * 1024 + lane * 16;
      int row = q >> 7;
      int soff = ((q >> 4) & 7) ^ (row & 7);
      {
        int gr = r0 + row; if (gr >= M) gr = M - 1;
        const u16* gp = A + (size_t)gr * K + kt + soff * 8;
        __builtin_amdgcn_global_load_lds(
            (const __attribute__((address_space(1))) void*)gp,
            (__attribute__((address_space(3))) void*)((char*)As + wid * 4096 + it * 1024),
            16, 0, 0);
      }
      {
        int gn = c0 + row;
        const u16* gp = Bt + (size_t)gn * K + kt + soff * 8;
        __builtin_amdgcn_global_load_lds(
            (const __attribute__((address_space(1))) void*)gp,
            (__attribute__((address_space(3))) void*)((char*)Bs + wid * 4096 + it * 1024),
            16, 0, 0);
      }
    }
    __syncthreads();
    const char* Ab = (const char*)As;
    const char* Bb = (const char*)Bs;
    #pragma unroll
    for (int kk = 0; kk < 2; kk++) {
      short8 a[4], b[4];
      #pragma unroll
      for (int m = 0; m < 4; m++) {
        int row = wr * 64 + m * 16 + lr;
        int off = (row << 7) + kk * 64 + lk * 16;
        off ^= (row & 7) << 4;
        a[m] = *(const short8*)(Ab + off);
      }
      #pragma unroll
      for (int nn = 0; nn < 4; nn++) {
        int row = wc * 64 + nn * 16 + lr;
        int off = (row << 7) + kk * 64 + lk * 16;
        off ^= (row & 7) << 4;
        b[nn] = *(const short8*)(Bb + off);
      }
      #pragma unroll
      for (int m = 0; m < 4; m++)
        #pragma unroll
        for (int nn = 0; nn < 4; nn++)
          acc[m][nn] = __builtin_amdgcn_mfma_f32_16x16x32_bf16(a[m], b[nn], acc[m][nn], 0, 0, 0);
    }
    __syncthreads();
  }
  #pragma unroll
  for (int m = 0; m < 4; m++)
    #pragma unroll
    for (int nn = 0; nn < 4; nn++)
      #pragma unroll
      for (int r = 0; r < 4; r++) {
        int row = r0 + wr * 64 + m * 16 + lk * 4 + r;
        if (row < M) {
          int col = c0 + wc * 64 + nn * 16 + lr;
          C[(size_t)row * Nc + col] = f2b(acc[m][nn][r]);
        }
      }
}

// ---------------- conv2 scores ----------------
__global__ void k_att_h1(const u16* __restrict__ hm, const float* __restrict__ att_s,
                         const float* __restrict__ att_d, float* __restrict__ s_out,
                         float* __restrict__ d_out, int N) {
  int n = blockIdx.x * (blockDim.x >> 6) + (threadIdx.x >> 6);
  int lane = threadIdx.x & 63;
  if (n >= N) return;
  const u32* row = (const u32*)(hm + (size_t)n * CH);
  u32 d = row[lane];
  float x0 = blo(d), x1 = bhi(d);
  float ps = x0 * att_s[2 * lane] + x1 * att_s[2 * lane + 1];
  float pd = x0 * att_d[2 * lane] + x1 * att_d[2 * lane + 1];
  #pragma unroll
  for (int off = 32; off; off >>= 1) {
    ps += __shfl_xor(ps, off);
    pd += __shfl_xor(pd, off);
  }
  if (lane == 0) { s_out[n] = ps; d_out[n] = pd; }
}

// ---------------- conv2 aggregation + bias + LN + ReLU + pool, HALF-WAVE PER NODE ----------------
__global__ __launch_bounds__(256) void k_agg2f(
    const u32* __restrict__ raw2, const int* __restrict__ indptr,
    const int* __restrict__ srcs, const float* __restrict__ as2,
    const float* __restrict__ ad2, const float* __restrict__ bias,
    const float* __restrict__ gam, const float* __restrict__ bet,
    const int* __restrict__ batch, float* __restrict__ psum, int N) {
  int t = threadIdx.x;
  int n = blockIdx.x * 8 + (t >> 5);
  if (n >= N) return;
  int hl = t & 31;
  int hbase = t & 32;
  int beg = indptr[n], end = indptr[n + 1];
  float adv = ad2[n];
  float dsum = 0.f, a0 = 0.f, a1 = 0.f, a2 = 0.f, a3 = 0.f;

  for (int base = beg; base < end; base += 32) {
    int cnt = min(32, end - base);
    int sreg = 0;
    float w = 0.f;
    if (hl < cnt) {
      sreg = srcs[base + hl];
      w = __expf(lrelu(as2[sreg] + adv));
    }
    int j = 0;
    for (; j + 8 <= cnt; j += 8) {
      int s0 = __shfl(sreg, hbase + j),     s1 = __shfl(sreg, hbase + j + 1);
      int s2 = __shfl(sreg, hbase + j + 2), s3 = __shfl(sreg, hbase + j + 3);
      int s4 = __shfl(sreg, hbase + j + 4), s5 = __shfl(sreg, hbase + j + 5);
      int s6 = __shfl(sreg, hbase + j + 6), s7 = __shfl(sreg, hbase + j + 7);
      uint2 d0 = *(const uint2*)(raw2 + (size_t)s0 * 64 + 2 * hl);
      uint2 d1 = *(const uint2*)(raw2 + (size_t)s1 * 64 + 2 * hl);
      uint2 d2 = *(const uint2*)(raw2 + (size_t)s2 * 64 + 2 * hl);
      uint2 d3 = *(const uint2*)(raw2 + (size_t)s3 * 64 + 2 * hl);
      uint2 d4 = *(const uint2*)(raw2 + (size_t)s4 * 64 + 2 * hl);
      uint2 d5 = *(const uint2*)(raw2 + (size_t)s5 * 64 + 2 * hl);
      uint2 d6 = *(const uint2*)(raw2 + (size_t)s6 * 64 + 2 * hl);
      uint2 d7 = *(const uint2*)(raw2 + (size_t)s7 * 64 + 2 * hl);
      float w0 = __shfl(w, hbase + j),     w1 = __shfl(w, hbase + j + 1);
      float w2 = __shfl(w, hbase + j + 2), w3 = __shfl(w, hbase + j + 3);
      float w4 = __shfl(w, hbase + j + 4), w5 = __shfl(w, hbase + j + 5);
      float w6 = __shfl(w, hbase + j + 6), w7 = __shfl(w, hbase + j + 7);
      dsum += (w0 + w1 + w2 + w3) + (w4 + w5 + w6 + w7);
      a0 += w0 * blo(d0.x) + w1 * blo(d1.x) + w2 * blo(d2.x) + w3 * blo(d3.x)
          + w4 * blo(d4.x) + w5 * blo(d5.x) + w6 * blo(d6.x) + w7 * blo(d7.x);
      a1 += w0 * bhi(d0.x) + w1 * bhi(d1.x) + w2 * bhi(d2.x) + w3 * bhi(d3.x)
          + w4 * bhi(d4.x) + w5 * bhi(d5.x) + w6 * bhi(d6.x) + w7 * bhi(d7.x);
      a2 += w0 * blo(d0.y) + w1 * blo(d1.y) + w2 * blo(d2.y) + w3 * blo(d3.y)
          + w4 * blo(d4.y) + w5 * blo(d5.y) + w6 * blo(d6.y) + w7 * blo(d7.y);
      a3 += w0 * bhi(d0.y) + w1 * bhi(d1.y) + w2 * bhi(d2.y) + w3 * bhi(d3.y)
          + w4 * bhi(d4.y) + w5 * bhi(d5.y) + w6 * bhi(d6.y) + w7 * bhi(d7.y);
    }
    for (; j < cnt; j++) {
      int sA = __shfl(sreg, hbase + j);
      float wA = __shfl(w, hbase + j);
      uint2 dA = *(const uint2*)(raw2 + (size_t)sA * 64 + 2 * hl);
      dsum += wA;
      a0 += wA * blo(dA.x); a1 += wA * bhi(dA.x);
      a2 += wA * blo(dA.y); a3 += wA * bhi(dA.y);
    }
  }
  float inv = 1.f / (dsum + 1e-16f);
  int c0 = 4 * hl;
  float v0 = a0 * inv + bias[c0];
  float v1 = a1 * inv + bias[c0 + 1];
  float v2 = a2 * inv + bias[c0 + 2];
  float v3 = a3 * inv + bias[c0 + 3];
  float s1 = (v0 + v1) + (v2 + v3);
  float s2 = (v0 * v0 + v1 * v1) + (v2 * v2 + v3 * v3);
  #pragma unroll
  for (int off = 16; off; off >>= 1) {
    s1 += __shfl_xor(s1, off);
    s2 += __shfl_xor(s2, off);
  }
  float mean = s1 * (1.f / 128.f);
  float var = s2 * (1.f / 128.f) - mean * mean;
  float rs = rsqrtf(var + 1e-5f);
  float y0 = fmaxf((v0 - mean) * rs * gam[c0] + bet[c0], 0.f);
  float y1 = fmaxf((v1 - mean) * rs * gam[c0 + 1] + bet[c0 + 1], 0.f);
  float y2 = fmaxf((v2 - mean) * rs * gam[c0 + 2] + bet[c0 + 2], 0.f);
  float y3 = fmaxf((v3 - mean) * rs * gam[c0 + 3] + bet[c0 + 3], 0.f);
  int g = batch[n];
  atomicAdd(&psum[g * 128 + c0], y0);
  atomicAdd(&psum[g * 128 + c0 + 1], y1);
  atomicAdd(&psum[g * 128 + c0 + 2], y2);
  atomicAdd(&psum[g * 128 + c0 + 3], y3);
}

// ---------------- MLP head (counts via binary search on sorted batch) ----------------
__global__ __launch_bounds__(128) void k_head(const float* __restrict__ psum,
    const int* __restrict__ batch, int N,
    const float* __restrict__ rW1, const float* __restrict__ rb1,
    const float* __restrict__ rg, const float* __restrict__ rbe,
    const float* __restrict__ rW2, const float* __restrict__ rb2,
    float* __restrict__ outp) {
  int g = blockIdx.x, t = threadIdx.x;
  __shared__ float pl[128];
  __shared__ float yv[32];
  __shared__ float rv[32];
  __shared__ float mv[2];
  __shared__ int scnt;
  if (t == 0) {
    int lo = 0, hi = N;
    while (lo < hi) { int mid = (lo + hi) >> 1; if (batch[mid] < g) lo = mid + 1; else hi = mid; }
    int lo2 = lo, hi2 = N;
    while (lo2 < hi2) { int mid = (lo2 + hi2) >> 1; if (batch[mid] < g + 1) lo2 = mid + 1; else hi2 = mid; }
    scnt = lo2 - lo;
  }
  __syncthreads();
  float cnt = fmaxf((float)scnt, 1.f);
  pl[t] = psum[g * 128 + t] / cnt;
  __syncthreads();
  if (t < 32) {
    float s = rb1[t];
    for (int c = 0; c < 128; c++) s += pl[c] * rW1[c * 32 + t];
    yv[t] = s;
  }
  __syncthreads();
  if (t == 0) {
    float s = 0.f, sq = 0.f;
    for (int j = 0; j < 32; j++) { s += yv[j]; sq += yv[j] * yv[j]; }
    float mean = s / 32.f;
    float var = sq / 32.f - mean * mean;
    mv[0] = mean; mv[1] = rsqrtf(var + 1e-5f);
  }
  __syncthreads();
  if (t < 32) {
    float y = (yv[t] - mv[0]) * mv[1] * rg[t] + rbe[t];
    rv[t] = fmaxf(y, 0.f);
  }
  __syncthreads();
  if (t < OUT_DIM) {
    float s = rb2[t];
    for (int j = 0; j < 32; j++) s += rv[j] * rW2[j * 8 + t];
    outp[g * 8 + t] = s;
  }
}

extern "C" void kernel_launch(void* const* d_in, const int* in_sizes, int n_in,
                              void* d_out, int out_size, void* d_ws, size_t ws_size,
                              hipStream_t stream) {
  const float* x    = (const float*)d_in[0];
  const int*   ei   = (const int*)d_in[1];
  const int*   batch= (const int*)d_in[3];
  const float* W1   = (const float*)d_in[4];
  const float* as1w = (const float*)d_in[5];
  const float* ad1w = (const float*)d_in[6];
  const float* b1   = (const float*)d_in[7];
  const float* g1   = (const float*)d_in[8];
  const float* be1  = (const float*)d_in[9];
  const float* W2   = (const float*)d_in[10];
  const float* as2w = (const float*)d_in[11];
  const float* ad2w = (const float*)d_in[12];
  const float* b2   = (const float*)d_in[13];
  const float* g2   = (const float*)d_in[14];
  const float* be2  = (const float*)d_in[15];
  const float* rW1  = (const float*)d_in[16];
  const float* rb1  = (const float*)d_in[17];
  const float* rg   = (const float*)d_in[18];
  const float* rbe  = (const float*)d_in[19];
  const float* rW2  = (const float*)d_in[20];
  const float* rb2  = (const float*)d_in[21];

  int N = in_sizes[0] / 128;
  int E = in_sizes[1] / 2;
  int ET = E + N;
  int nb = (N + 255) / 256;

  char* p = (char*)d_ws;
  u16* x_b   = (u16*)p; p += (size_t)N * 128 * 2;
  u16* aggx  = (u16*)p; p += (size_t)N * 512 * 2;
  u16* raw1  = (u16*)p; p += (size_t)N * 512 * 2;
  u16* h1_b  = (u16*)p; p += (size_t)N * 512 * 2;
  u16* raw2b = (u16*)p; p += (size_t)N * 128 * 2;
  u16* W1t   = (u16*)p; p += 512 * 128 * 2;
  u16* W2t   = (u16*)p; p += 128 * 512 * 2;
  float* ws  = (float*)p; p += 128 * 8 * 4;
  float* sa1 = (float*)p; p += (size_t)N * 4 * 4;
  float* da1 = (float*)p; p += (size_t)N * 4 * 4;
  float* sa2 = (float*)p; p += (size_t)N * 4;
  float* da2 = (float*)p; p += (size_t)N * 4;
  float* psum = (float*)p; p += GRAPHS * CH * 4;
  int* counts = (int*)p; p += (size_t)N * 4;
  int* indptr = (int*)p; p += (size_t)(N + 1) * 4;
  int* cursor = (int*)p; p += (size_t)N * 4;
  int* bsum   = (int*)p; p += (size_t)nb * 4;
  int* boff   = (int*)p; p += (size_t)nb * 4;
  int* srcs   = (int*)p; p += (size_t)ET * 4;

  hipMemsetAsync(counts, 0, (size_t)N * sizeof(int), stream);
  hipMemsetAsync(psum, 0, (size_t)GRAPHS * CH * sizeof(float), stream);

  int eb = (ET + 255) / 256;
  k_count<<<eb, 256, 0, stream>>>(ei, counts, E, N);
  k_scanA<<<nb, 256, 0, stream>>>(counts, bsum, N);
  k_scanB<<<1, 1024, 0, stream>>>(bsum, boff, nb);
  k_scanC<<<nb, 256, 0, stream>>>(counts, boff, indptr, cursor, N);
  k_scatter<<<eb, 256, 0, stream>>>(ei, cursor, srcs, E, N);

  // conversions + score matrices
  k_wt<<<(512 * 128 + 255) / 256, 256, 0, stream>>>(W1, W1t, 128, 512);
  k_wt<<<(512 * 128 + 255) / 256, 256, 0, stream>>>(W2, W2t, 512, 128);
  k_ws<<<1, 256, 0, stream>>>(W1, as1w, ad1w, ws);
  k_prep<<<(N + 3) / 4, 256, 0, stream>>>(x, ws, (u32*)x_b, (float4*)sa1, (float4*)da1, N);

  // conv1: aggregate x (half-wave per node), per-head GEMM (+bias), LN+ReLU
  k_aggx<<<(N + 7) / 8, 256, 0, stream>>>((const u32*)x_b, indptr, srcs,
                                          (const float4*)sa1, (const float4*)da1,
                                          (u32*)aggx, N);
  dim3 gridh((N + 127) / 128, 4);
  k_gemm_head<<<gridh, 256, 0, stream>>>(aggx, W1t, b1, raw1, N);
  k_ln512<<<(N + 3) / 4, 256, 0, stream>>>(raw1, g1, be1, h1_b, N);

  // conv2
  dim3 grid2((N + 127) / 128, 1);
  k_gemm_bf16<<<grid2, 256, 0, stream>>>(h1_b, W2t, raw2b, N, 128, 512);
  k_att_h1<<<(N + 3) / 4, 256, 0, stream>>>(raw2b, as2w, ad2w, sa2, da2, N);
  k_agg2f<<<(N + 7) / 8, 256, 0, stream>>>((const u32*)raw2b, indptr, srcs, sa2, da2,
                                           b2, g2, be2, batch, psum, N);

  // head (counts via binary search, no k_cnt)
  k_head<<<GRAPHS, 128, 0, stream>>>(psum, batch, N, rW1, rb1, rg, rbe, rW2, rb2,
                                     (float*)d_out);
}

// Round 8
// 411.823 us; speedup vs baseline: 1.2033x; 1.2033x over previous
//
#include <hip/hip_runtime.h>
#include <math.h>

#define HEADS 4
#define CH 128
#define HC 512
#define GRAPHS 128
#define OUT_DIM 8

typedef unsigned short u16;
typedef unsigned int u32;
typedef short short8 __attribute__((ext_vector_type(8)));
typedef float f32x4 __attribute__((ext_vector_type(4)));

__device__ inline u16 f2b(float f) {
  u32 u = __float_as_uint(f);
  u32 r = u + 0x7FFFu + ((u >> 16) & 1u);
  return (u16)(r >> 16);
}
__device__ inline float blo(u32 d) { return __uint_as_float(d << 16); }
__device__ inline float bhi(u32 d) { return __uint_as_float(d & 0xffff0000u); }
__device__ inline float lrelu(float v) { return v > 0.f ? v : 0.2f * v; }
// wave-uniform broadcast via v_readlane (SGPR index) — never ds_bpermute
__device__ inline int rdl(int v, int l) { return __builtin_amdgcn_readlane(v, l); }
__device__ inline float rdlf(float v, int l) {
  return __int_as_float(__builtin_amdgcn_readlane(__float_as_int(v), l));
}

// ---------------- CSR build ----------------
__global__ void k_count(const int* __restrict__ ei, int* __restrict__ counts, int E, int N) {
  int i = blockIdx.x * blockDim.x + threadIdx.x;
  int total = E + N;
  if (i >= total) return;
  int dst = (i < E) ? ei[E + i] : (i - E);
  atomicAdd(&counts[dst], 1);
}

__global__ __launch_bounds__(256) void k_scanA(const int* __restrict__ counts,
                                               int* __restrict__ bsum, int N) {
  __shared__ int sh[256];
  int b = blockIdx.x, t = threadIdx.x, i = b * 256 + t;
  sh[t] = (i < N) ? counts[i] : 0;
  __syncthreads();
  for (int off = 128; off; off >>= 1) {
    if (t < off) sh[t] += sh[t + off];
    __syncthreads();
  }
  if (t == 0) bsum[b] = sh[0];
}

__global__ __launch_bounds__(1024) void k_scanB(const int* __restrict__ bsum,
                                                int* __restrict__ boff, int nb) {
  __shared__ int sh[1024];
  int t = threadIdx.x;
  sh[t] = (t < nb) ? bsum[t] : 0;
  __syncthreads();
  for (int off = 1; off < 1024; off <<= 1) {
    int v = sh[t];
    int u = (t >= off) ? sh[t - off] : 0;
    __syncthreads();
    sh[t] = v + u;
    __syncthreads();
  }
  if (t < nb) boff[t] = (t == 0) ? 0 : sh[t - 1];
}

__global__ __launch_bounds__(256) void k_scanC(const int* __restrict__ counts,
                                               const int* __restrict__ boff,
                                               int* __restrict__ indptr,
                                               int* __restrict__ cursor, int N) {
  __shared__ int sh[256];
  int b = blockIdx.x, t = threadIdx.x, i = b * 256 + t;
  int v = (i < N) ? counts[i] : 0;
  sh[t] = v;
  __syncthreads();
  for (int off = 1; off < 256; off <<= 1) {
    int a = sh[t];
    int u = (t >= off) ? sh[t - off] : 0;
    __syncthreads();
    sh[t] = a + u;
    __syncthreads();
  }
  if (i < N) {
    int excl = boff[b] + sh[t] - v;
    indptr[i] = excl;
    cursor[i] = excl;
    if (i == N - 1) indptr[N] = excl + v;
  }
}

__global__ void k_scatter(const int* __restrict__ ei, int* __restrict__ cursor,
                          int* __restrict__ srcs, int E, int N) {
  int i = blockIdx.x * blockDim.x + threadIdx.x;
  int total = E + N;
  if (i >= total) return;
  int src, dst;
  if (i < E) { src = ei[i]; dst = ei[E + i]; } else { src = i - E; dst = i - E; }
  int pos = atomicAdd(&cursor[dst], 1);
  srcs[pos] = src;
}

// ---------------- converters ----------------
// W [K][Nc] fp32 -> Wt [Nc][K] bf16 (transposed)
__global__ void k_wt(const float* __restrict__ W, u16* __restrict__ Wt, int K, int Nc) {
  int i = blockIdx.x * blockDim.x + threadIdx.x;
  if (i >= K * Nc) return;
  int n = i / K, k = i - n * K;
  Wt[i] = f2b(W[(size_t)k * Nc + n]);
}

// ws[k][o]: o in 0..3 = src heads, 4..7 = dst heads.  ws = W1_head @ att_head
__global__ __launch_bounds__(256) void k_ws(const float* __restrict__ W1,
                                            const float* __restrict__ as1,
                                            const float* __restrict__ ad1,
                                            float* __restrict__ ws) {
  int t = threadIdx.x;
  #pragma unroll
  for (int r = 0; r < 4; r++) {
    int idx = r * 256 + t;       // 0..1023
    int k = idx >> 3, o = idx & 7, h = o & 3;
    const float* av = ((o < 4) ? as1 : ad1) + h * CH;
    const float* wrow = W1 + (size_t)k * HC + h * CH;
    float s = 0.f;
    for (int c = 0; c < CH; c++) s += wrow[c] * av[c];
    ws[idx] = s;
  }
}

// ---------------- fused x->bf16 conversion + conv1 scores (wave per node) ----------------
__global__ void k_prep(const float* __restrict__ x, const float* __restrict__ ws,
                       u32* __restrict__ xb, float4* __restrict__ sa1,
                       float4* __restrict__ da1, int N) {
  int n = blockIdx.x * (blockDim.x >> 6) + (threadIdx.x >> 6);
  int lane = threadIdx.x & 63;
  if (n >= N) return;
  float2 v = ((const float2*)(x + (size_t)n * 128))[lane];
  xb[(size_t)n * 64 + lane] = (u32)f2b(v.x) | ((u32)f2b(v.y) << 16);
  const float* w0 = ws + (2 * lane) * 8;
  const float* w1 = ws + (2 * lane + 1) * 8;
  float p[8];
  #pragma unroll
  for (int o = 0; o < 8; o++) p[o] = v.x * w0[o] + v.y * w1[o];
  #pragma unroll
  for (int off = 32; off; off >>= 1)
    #pragma unroll
    for (int o = 0; o < 8; o++) p[o] += __shfl_xor(p[o], off);
  if (lane == 0) {
    sa1[n] = make_float4(p[0], p[1], p[2], p[3]);
    da1[n] = make_float4(p[4], p[5], p[6], p[7]);
  }
}

// ---------------- conv1 aggregation over x (bf16), 4 heads ----------------
// Full wave per node, TWO nodes per wave interleaved; readlane broadcasts.
__global__ __launch_bounds__(256) void k_aggx(
    const u32* __restrict__ xb, const int* __restrict__ indptr,
    const int* __restrict__ srcs, const float4* __restrict__ as1,
    const float4* __restrict__ ad1, u32* __restrict__ aggx, int N) {
  int t = threadIdx.x;
  int lane = t & 63, wid = t >> 6;
  int n0 = blockIdx.x * 8 + wid * 2;
  if (n0 >= N) return;
  int n1 = n0 + 1;
  bool has1 = n1 < N;
  int beg0 = indptr[n0], end0 = indptr[n0 + 1];
  int beg1 = end0, end1 = has1 ? indptr[n1 + 1] : end0;
  int deg0 = end0 - beg0, deg1 = end1 - beg1;
  float4 ad0 = ad1[n0];
  float4 adv1 = has1 ? ad1[n1] : make_float4(0.f, 0.f, 0.f, 0.f);

  if (deg0 <= 64 && deg1 <= 64) {
    int s0 = 0, s1 = 0;
    float w00 = 0, w01 = 0, w02 = 0, w03 = 0;
    float w10 = 0, w11 = 0, w12 = 0, w13 = 0;
    if (lane < deg0) {
      s0 = srcs[beg0 + lane];
      float4 a = as1[s0];
      w00 = __expf(lrelu(a.x + ad0.x)); w01 = __expf(lrelu(a.y + ad0.y));
      w02 = __expf(lrelu(a.z + ad0.z)); w03 = __expf(lrelu(a.w + ad0.w));
    }
    if (lane < deg1) {
      s1 = srcs[beg1 + lane];
      float4 a = as1[s1];
      w10 = __expf(lrelu(a.x + adv1.x)); w11 = __expf(lrelu(a.y + adv1.y));
      w12 = __expf(lrelu(a.z + adv1.z)); w13 = __expf(lrelu(a.w + adv1.w));
    }
    float e00 = 0, e01 = 0, e02 = 0, e03 = 0;
    float e10 = 0, e11 = 0, e12 = 0, e13 = 0;
    float c00 = 0, c01 = 0, c10 = 0, c11 = 0, c20 = 0, c21 = 0, c30 = 0, c31 = 0;
    float d00 = 0, d01 = 0, d10 = 0, d11 = 0, d20 = 0, d21 = 0, d30 = 0, d31 = 0;
    int dmax = deg0 > deg1 ? deg0 : deg1;
    int dpad = (dmax + 1) & ~1;
    for (int j = 0; j < dpad; j += 2) {
      int pA = rdl(s0, j), pB = rdl(s0, j + 1);
      int qA = rdl(s1, j), qB = rdl(s1, j + 1);
      u32 dA = xb[(size_t)pA * 64 + lane];
      u32 dB = xb[(size_t)pB * 64 + lane];
      u32 eA = xb[(size_t)qA * 64 + lane];
      u32 eB = xb[(size_t)qB * 64 + lane];
      float xA0 = blo(dA), xA1 = bhi(dA), xB0 = blo(dB), xB1 = bhi(dB);
      float yA0 = blo(eA), yA1 = bhi(eA), yB0 = blo(eB), yB1 = bhi(eB);
      float a, b;
      a = rdlf(w00, j); b = rdlf(w00, j + 1); e00 += a + b;
      c00 += a * xA0 + b * xB0; c01 += a * xA1 + b * xB1;
      a = rdlf(w01, j); b = rdlf(w01, j + 1); e01 += a + b;
      c10 += a * xA0 + b * xB0; c11 += a * xA1 + b * xB1;
      a = rdlf(w02, j); b = rdlf(w02, j + 1); e02 += a + b;
      c20 += a * xA0 + b * xB0; c21 += a * xA1 + b * xB1;
      a = rdlf(w03, j); b = rdlf(w03, j + 1); e03 += a + b;
      c30 += a * xA0 + b * xB0; c31 += a * xA1 + b * xB1;
      a = rdlf(w10, j); b = rdlf(w10, j + 1); e10 += a + b;
      d00 += a * yA0 + b * yB0; d01 += a * yA1 + b * yB1;
      a = rdlf(w11, j); b = rdlf(w11, j + 1); e11 += a + b;
      d10 += a * yA0 + b * yB0; d11 += a * yA1 + b * yB1;
      a = rdlf(w12, j); b = rdlf(w12, j + 1); e12 += a + b;
      d20 += a * yA0 + b * yB0; d21 += a * yA1 + b * yB1;
      a = rdlf(w13, j); b = rdlf(w13, j + 1); e13 += a + b;
      d30 += a * yA0 + b * yB0; d31 += a * yA1 + b * yB1;
    }
    {
      float i0 = 1.f / (e00 + 1e-16f), i1 = 1.f / (e01 + 1e-16f);
      float i2 = 1.f / (e02 + 1e-16f), i3 = 1.f / (e03 + 1e-16f);
      u32* orow = aggx + (size_t)n0 * 256;
      orow[lane]       = (u32)f2b(c00 * i0) | ((u32)f2b(c01 * i0) << 16);
      orow[64 + lane]  = (u32)f2b(c10 * i1) | ((u32)f2b(c11 * i1) << 16);
      orow[128 + lane] = (u32)f2b(c20 * i2) | ((u32)f2b(c21 * i2) << 16);
      orow[192 + lane] = (u32)f2b(c30 * i3) | ((u32)f2b(c31 * i3) << 16);
    }
    if (has1) {
      float i0 = 1.f / (e10 + 1e-16f), i1 = 1.f / (e11 + 1e-16f);
      float i2 = 1.f / (e12 + 1e-16f), i3 = 1.f / (e13 + 1e-16f);
      u32* orow = aggx + (size_t)n1 * 256;
      orow[lane]       = (u32)f2b(d00 * i0) | ((u32)f2b(d01 * i0) << 16);
      orow[64 + lane]  = (u32)f2b(d10 * i1) | ((u32)f2b(d11 * i1) << 16);
      orow[128 + lane] = (u32)f2b(d20 * i2) | ((u32)f2b(d21 * i2) << 16);
      orow[192 + lane] = (u32)f2b(d30 * i3) | ((u32)f2b(d31 * i3) << 16);
    }
    return;
  }
  // slow path (deg > 64): chunked, one node at a time
  for (int pass = 0; pass < 2; pass++) {
    if (pass == 1 && !has1) break;
    int n = pass ? n1 : n0;
    int beg = pass ? beg1 : beg0;
    int end = pass ? end1 : end0;
    float4 ad = pass ? adv1 : ad0;
    float e0 = 0, e1 = 0, e2 = 0, e3 = 0;
    float c00 = 0, c01 = 0, c10 = 0, c11 = 0, c20 = 0, c21 = 0, c30 = 0, c31 = 0;
    for (int base = beg; base < end; base += 64) {
      int cnt = min(64, end - base);
      int sreg = 0;
      float w0 = 0, w1 = 0, w2 = 0, w3 = 0;
      if (lane < cnt) {
        sreg = srcs[base + lane];
        float4 a = as1[sreg];
        w0 = __expf(lrelu(a.x + ad.x)); w1 = __expf(lrelu(a.y + ad.y));
        w2 = __expf(lrelu(a.z + ad.z)); w3 = __expf(lrelu(a.w + ad.w));
      }
      int cpad = (cnt + 1) & ~1;
      for (int j = 0; j < cpad; j += 2) {
        int pA = rdl(sreg, j), pB = rdl(sreg, j + 1);
        u32 dA = xb[(size_t)pA * 64 + lane];
        u32 dB = xb[(size_t)pB * 64 + lane];
        float xA0 = blo(dA), xA1 = bhi(dA), xB0 = blo(dB), xB1 = bhi(dB);
        float a, b;
        a = rdlf(w0, j); b = rdlf(w0, j + 1); e0 += a + b;
        c00 += a * xA0 + b * xB0; c01 += a * xA1 + b * xB1;
        a = rdlf(w1, j); b = rdlf(w1, j + 1); e1 += a + b;
        c10 += a * xA0 + b * xB0; c11 += a * xA1 + b * xB1;
        a = rdlf(w2, j); b = rdlf(w2, j + 1); e2 += a + b;
        c20 += a * xA0 + b * xB0; c21 += a * xA1 + b * xB1;
        a = rdlf(w3, j); b = rdlf(w3, j + 1); e3 += a + b;
        c30 += a * xA0 + b * xB0; c31 += a * xA1 + b * xB1;
      }
    }
    float i0 = 1.f / (e0 + 1e-16f), i1 = 1.f / (e1 + 1e-16f);
    float i2 = 1.f / (e2 + 1e-16f), i3 = 1.f / (e3 + 1e-16f);
    u32* orow = aggx + (size_t)n * 256;
    orow[lane]       = (u32)f2b(c00 * i0) | ((u32)f2b(c01 * i0) << 16);
    orow[64 + lane]  = (u32)f2b(c10 * i1) | ((u32)f2b(c11 * i1) << 16);
    orow[128 + lane] = (u32)f2b(c20 * i2) | ((u32)f2b(c21 * i2) << 16);
    orow[192 + lane] = (u32)f2b(c30 * i3) | ((u32)f2b(c31 * i3) << 16);
  }
}

// ---------------- per-head GEMM: raw1[:, hC:(h+1)C] = aggx[:,h,:] @ W1[:,hC:(h+1)C] + b1 ----------------
__global__ __launch_bounds__(256) void k_gemm_head(
    const u16* __restrict__ A,    // aggx [M][512]
    const u16* __restrict__ Bt,   // W1t  [512][128]
    const float* __restrict__ bias,
    u16* __restrict__ C,          // raw1 [M][512]
    int M) {
  __shared__ u16 As[128 * 64];
  __shared__ u16 Bs[128 * 64];
  int t = threadIdx.x;
  int lane = t & 63, wid = t >> 6;
  int wr = wid >> 1, wc = wid & 1;
  int r0 = blockIdx.x * 128;
  int hh = blockIdx.y;
  const u16* Ah = A + hh * 128;
  const u16* Bh = Bt + (size_t)hh * 128 * 128;
  int lr = lane & 15, lk = lane >> 4;
  f32x4 acc[4][4] = {};
  for (int kt = 0; kt < 128; kt += 64) {
    #pragma unroll
    for (int it = 0; it < 4; it++) {
      int q = wid * 4096 + it * 1024 + lane * 16;
      int row = q >> 7;
      int soff = ((q >> 4) & 7) ^ (row & 7);
      {
        int gr = r0 + row; if (gr >= M) gr = M - 1;
        const u16* gp = Ah + (size_t)gr * 512 + kt + soff * 8;
        __builtin_amdgcn_global_load_lds(
            (const __attribute__((address_space(1))) void*)gp,
            (__attribute__((address_space(3))) void*)((char*)As + wid * 4096 + it * 1024),
            16, 0, 0);
      }
      {
        const u16* gp = Bh + (size_t)row * 128 + kt + soff * 8;
        __builtin_amdgcn_global_load_lds(
            (const __attribute__((address_space(1))) void*)gp,
            (__attribute__((address_space(3))) void*)((char*)Bs + wid * 4096 + it * 1024),
            16, 0, 0);
      }
    }
    __syncthreads();
    const char* Ab = (const char*)As;
    const char* Bb = (const char*)Bs;
    #pragma unroll
    for (int kk = 0; kk < 2; kk++) {
      short8 a[4], b[4];
      #pragma unroll
      for (int m = 0; m < 4; m++) {
        int row = wr * 64 + m * 16 + lr;
        int off = (row << 7) + kk * 64 + lk * 16;
        off ^= (row & 7) << 4;
        a[m] = *(const short8*)(Ab + off);
      }
      #pragma unroll
      for (int nn = 0; nn < 4; nn++) {
        int row = wc * 64 + nn * 16 + lr;
        int off = (row << 7) + kk * 64 + lk * 16;
        off ^= (row & 7) << 4;
        b[nn] = *(const short8*)(Bb + off);
      }
      #pragma unroll
      for (int m = 0; m < 4; m++)
        #pragma unroll
        for (int nn = 0; nn < 4; nn++)
          acc[m][nn] = __builtin_amdgcn_mfma_f32_16x16x32_bf16(a[m], b[nn], acc[m][nn], 0, 0, 0);
    }
    __syncthreads();
  }
  #pragma unroll
  for (int m = 0; m < 4; m++)
    #pragma unroll
    for (int nn = 0; nn < 4; nn++)
      #pragma unroll
      for (int r = 0; r < 4; r++) {
        int row = r0 + wr * 64 + m * 16 + lk * 4 + r;
        if (row < M) {
          int gcol = hh * 128 + wc * 64 + nn * 16 + lr;
          C[(size_t)row * 512 + gcol] = f2b(acc[m][nn][r] + bias[gcol]);
        }
      }
}

// ---------------- LN+ReLU over 512 channels (bf16 in/out) ----------------
__global__ __launch_bounds__(256) void k_ln512(const u16* __restrict__ raw,
                                               const float* __restrict__ gam,
                                               const float* __restrict__ bet,
                                               u16* __restrict__ out, int N) {
  int n = blockIdx.x * 4 + (threadIdx.x >> 6);
  int lane = threadIdx.x & 63;
  if (n >= N) return;
  const uint4* r = (const uint4*)(raw + (size_t)n * 512);
  uint4 q = r[lane];
  float v[8];
  v[0] = blo(q.x); v[1] = bhi(q.x); v[2] = blo(q.y); v[3] = bhi(q.y);
  v[4] = blo(q.z); v[5] = bhi(q.z); v[6] = blo(q.w); v[7] = bhi(q.w);
  float s1 = 0.f, s2 = 0.f;
  #pragma unroll
  for (int j = 0; j < 8; j++) { s1 += v[j]; s2 += v[j] * v[j]; }
  #pragma unroll
  for (int off = 32; off; off >>= 1) {
    s1 += __shfl_xor(s1, off);
    s2 += __shfl_xor(s2, off);
  }
  float mean = s1 * (1.f / 512.f);
  float var = s2 * (1.f / 512.f) - mean * mean;
  float rs = rsqrtf(var + 1e-5f);
  u32 o[4];
  #pragma unroll
  for (int j = 0; j < 4; j++) {
    int ch = lane * 8 + 2 * j;
    float y0 = fmaxf((v[2 * j] - mean) * rs * gam[ch] + bet[ch], 0.f);
    float y1 = fmaxf((v[2 * j + 1] - mean) * rs * gam[ch + 1] + bet[ch + 1], 0.f);
    o[j] = (u32)f2b(y0) | ((u32)f2b(y1) << 16);
  }
  ((uint4*)(out + (size_t)n * 512))[lane] = make_uint4(o[0], o[1], o[2], o[3]);
}

// ---------------- bf16 MFMA GEMM (conv2): C[M][128] = A[M][512] * Bt[128][512]^T ----------------
__global__ __launch_bounds__(256) void k_gemm_bf16(
    const u16* __restrict__ A, const u16* __restrict__ Bt,
    u16* __restrict__ C, int M, int Nc, int K) {
  __shared__ u16 As[128 * 64];
  __shared__ u16 Bs[128 * 64];
  int t = threadIdx.x;
  int lane = t & 63, wid = t >> 6;
  int wr = wid >> 1, wc = wid & 1;
  int r0 = blockIdx.x * 128, c0 = blockIdx.y * 128;
  int lr = lane & 15, lk = lane >> 4;
  f32x4 acc[4][4] = {};
  for (int kt = 0; kt < K; kt += 64) {
    #pragma unroll
    for (int it = 0; it < 4; it++) {
      int q = wid * 4096 + it * 1024 + lane * 16;
      int row = q >> 7;
      int soff = ((q >> 4) & 7) ^ (row & 7);
      {
        int gr = r0 + row; if (gr >= M) gr = M - 1;
        const u16* gp = A + (size_t)gr * K + kt + soff * 8;
        __builtin_amdgcn_global_load_lds(
            (const __attribute__((address_space(1))) void*)gp,
            (__attribute__((address_space(3))) void*)((char*)As + wid * 4096 + it * 1024),
            16, 0, 0);
      }
      {
        int gn = c0 + row;
        const u16* gp = Bt + (size_t)gn * K + kt + soff * 8;
        __builtin_amdgcn_global_load_lds(
            (const __attribute__((address_space(1))) void*)gp,
            (__attribute__((address_space(3))) void*)((char*)Bs + wid * 4096 + it * 1024),
            16, 0, 0);
      }
    }
    __syncthreads();
    const char* Ab = (const char*)As;
    const char* Bb = (const char*)Bs;
    #pragma unroll
    for (int kk = 0; kk < 2; kk++) {
      short8 a[4], b[4];
      #pragma unroll
      for (int m = 0; m < 4; m++) {
        int row = wr * 64 + m * 16 + lr;
        int off = (row << 7) + kk * 64 + lk * 16;
        off ^= (row & 7) << 4;
        a[m] = *(const short8*)(Ab + off);
      }
      #pragma unroll
      for (int nn = 0; nn < 4; nn++) {
        int row = wc * 64 + nn * 16 + lr;
        int off = (row << 7) + kk * 64 + lk * 16;
        off ^= (row & 7) << 4;
        b[nn] = *(const short8*)(Bb + off);
      }
      #pragma unroll
      for (int m = 0; m < 4; m++)
        #pragma unroll
        for (int nn = 0; nn < 4; nn++)
          acc[m][nn] = __builtin_amdgcn_mfma_f32_16x16x32_bf16(a[m], b[nn], acc[m][nn], 0, 0, 0);
    }
    __syncthreads();
  }
  #pragma unroll
  for (int m = 0; m < 4; m++)
    #pragma unroll
    for (int nn = 0; nn < 4; nn++)
      #pragma unroll
      for (int r = 0; r < 4; r++) {
        int row = r0 + wr * 64 + m * 16 + lk * 4 + r;
        if (row < M) {
          int col = c0 + wc * 64 + nn * 16 + lr;
          C[(size_t)row * Nc + col] = f2b(acc[m][nn][r]);
        }
      }
}

// ---------------- conv2 scores ----------------
__global__ void k_att_h1(const u16* __restrict__ hm, const float* __restrict__ att_s,
                         const float* __restrict__ att_d, float* __restrict__ s_out,
                         float* __restrict__ d_out, int N) {
  int n = blockIdx.x * (blockDim.x >> 6) + (threadIdx.x >> 6);
  int lane = threadIdx.x & 63;
  if (n >= N) return;
  const u32* row = (const u32*)(hm + (size_t)n * CH);
  u32 d = row[lane];
  float x0 = blo(d), x1 = bhi(d);
  float ps = x0 * att_s[2 * lane] + x1 * att_s[2 * lane + 1];
  float pd = x0 * att_d[2 * lane] + x1 * att_d[2 * lane + 1];
  #pragma unroll
  for (int off = 32; off; off >>= 1) {
    ps += __shfl_xor(ps, off);
    pd += __shfl_xor(pd, off);
  }
  if (lane == 0) { s_out[n] = ps; d_out[n] = pd; }
}

// ---------------- conv2 aggregation + bias + LN + ReLU + pool ----------------
// Full wave per node, TWO nodes per wave interleaved; readlane broadcasts.
__global__ __launch_bounds__(256) void k_agg2f(
    const u32* __restrict__ raw2, const int* __restrict__ indptr,
    const int* __restrict__ srcs, const float* __restrict__ as2,
    const float* __restrict__ ad2, const float* __restrict__ bias,
    const float* __restrict__ gam, const float* __restrict__ bet,
    const int* __restrict__ batch, float* __restrict__ psum, int N) {
  int t = threadIdx.x;
  int lane = t & 63, wid = t >> 6;
  int n0 = blockIdx.x * 8 + wid * 2;
  if (n0 >= N) return;
  int n1 = n0 + 1;
  bool has1 = n1 < N;
  int beg0 = indptr[n0], end0 = indptr[n0 + 1];
  int beg1 = end0, end1 = has1 ? indptr[n1 + 1] : end0;
  int deg0 = end0 - beg0, deg1 = end1 - beg1;
  float adv0 = ad2[n0];
  float adv1 = has1 ? ad2[n1] : 0.f;
  float ds0 = 0.f, ds1 = 0.f;
  float a00 = 0.f, a01 = 0.f, a10 = 0.f, a11 = 0.f;

  if (deg0 <= 64 && deg1 <= 64) {
    int s0 = 0, s1r = 0;
    float w0 = 0.f, w1 = 0.f;
    if (lane < deg0) { s0 = srcs[beg0 + lane]; w0 = __expf(lrelu(as2[s0] + adv0)); }
    if (lane < deg1) { s1r = srcs[beg1 + lane]; w1 = __expf(lrelu(as2[s1r] + adv1)); }
    int dmax = deg0 > deg1 ? deg0 : deg1;
    int dpad = (dmax + 3) & ~3;
    for (int j = 0; j < dpad; j += 4) {
      int pA = rdl(s0, j), pB = rdl(s0, j + 1), pC = rdl(s0, j + 2), pD = rdl(s0, j + 3);
      int qA = rdl(s1r, j), qB = rdl(s1r, j + 1), qC = rdl(s1r, j + 2), qD = rdl(s1r, j + 3);
      u32 dA = raw2[(size_t)pA * 64 + lane];
      u32 dB = raw2[(size_t)pB * 64 + lane];
      u32 dC = raw2[(size_t)pC * 64 + lane];
      u32 dD = raw2[(size_t)pD * 64 + lane];
      u32 eA = raw2[(size_t)qA * 64 + lane];
      u32 eB = raw2[(size_t)qB * 64 + lane];
      u32 eC = raw2[(size_t)qC * 64 + lane];
      u32 eD = raw2[(size_t)qD * 64 + lane];
      float wA = rdlf(w0, j), wB = rdlf(w0, j + 1), wC = rdlf(w0, j + 2), wD = rdlf(w0, j + 3);
      float vA = rdlf(w1, j), vB = rdlf(w1, j + 1), vC = rdlf(w1, j + 2), vD = rdlf(w1, j + 3);
      ds0 += (wA + wB) + (wC + wD);
      ds1 += (vA + vB) + (vC + vD);
      a00 += wA * blo(dA) + wB * blo(dB) + wC * blo(dC) + wD * blo(dD);
      a01 += wA * bhi(dA) + wB * bhi(dB) + wC * bhi(dC) + wD * bhi(dD);
      a10 += vA * blo(eA) + vB * blo(eB) + vC * blo(eC) + vD * blo(eD);
      a11 += vA * bhi(eA) + vB * bhi(eB) + vC * bhi(eC) + vD * bhi(eD);
    }
  } else {
    // slow path: chunked, node0 then node1
    for (int pass = 0; pass < 2; pass++) {
      if (pass == 1 && !has1) break;
      int beg = pass ? beg1 : beg0;
      int end = pass ? end1 : end0;
      float adv = pass ? adv1 : adv0;
      for (int base = beg; base < end; base += 64) {
        int cnt = min(64, end - base);
        int sreg = 0;
        float w = 0.f;
        if (lane < cnt) { sreg = srcs[base + lane]; w = __expf(lrelu(as2[sreg] + adv)); }
        int cpad = (cnt + 3) & ~3;
        for (int j = 0; j < cpad; j += 4) {
          int pA = rdl(sreg, j), pB = rdl(sreg, j + 1);
          int pC = rdl(sreg, j + 2), pD = rdl(sreg, j + 3);
          u32 dA = raw2[(size_t)pA * 64 + lane];
          u32 dB = raw2[(size_t)pB * 64 + lane];
          u32 dC = raw2[(size_t)pC * 64 + lane];
          u32 dD = raw2[(size_t)pD * 64 + lane];
          float wA = rdlf(w, j), wB = rdlf(w, j + 1);
          float wC = rdlf(w, j + 2), wD = rdlf(w, j + 3);
          float lo = wA * blo(dA) + wB * blo(dB) + wC * blo(dC) + wD * blo(dD);
          float hi = wA * bhi(dA) + wB * bhi(dB) + wC * bhi(dC) + wD * bhi(dD);
          float sw = (wA + wB) + (wC + wD);
          if (pass) { ds1 += sw; a10 += lo; a11 += hi; }
          else      { ds0 += sw; a00 += lo; a01 += hi; }
        }
      }
    }
  }

  // LN + ReLU + pool, both nodes (butterflies interleaved)
  float inv0 = 1.f / (ds0 + 1e-16f);
  float v00 = a00 * inv0 + bias[2 * lane];
  float v01 = a01 * inv0 + bias[2 * lane + 1];
  float s1a = v00 + v01, s2a = v00 * v00 + v01 * v01;
  float inv1 = 1.f / (ds1 + 1e-16f);
  float v10 = a10 * inv1 + bias[2 * lane];
  float v11 = a11 * inv1 + bias[2 * lane + 1];
  float s1b = v10 + v11, s2b = v10 * v10 + v11 * v11;
  #pragma unroll
  for (int off = 32; off; off >>= 1) {
    s1a += __shfl_xor(s1a, off);
    s2a += __shfl_xor(s2a, off);
    s1b += __shfl_xor(s1b, off);
    s2b += __shfl_xor(s2b, off);
  }
  {
    float mean = s1a * (1.f / 128.f);
    float var = s2a * (1.f / 128.f) - mean * mean;
    float rs = rsqrtf(var + 1e-5f);
    float y0 = fmaxf((v00 - mean) * rs * gam[2 * lane] + bet[2 * lane], 0.f);
    float y1 = fmaxf((v01 - mean) * rs * gam[2 * lane + 1] + bet[2 * lane + 1], 0.f);
    int g = batch[n0];
    atomicAdd(&psum[g * 128 + 2 * lane], y0);
    atomicAdd(&psum[g * 128 + 2 * lane + 1], y1);
  }
  if (has1) {
    float mean = s1b * (1.f / 128.f);
    float var = s2b * (1.f / 128.f) - mean * mean;
    float rs = rsqrtf(var + 1e-5f);
    float y0 = fmaxf((v10 - mean) * rs * gam[2 * lane] + bet[2 * lane], 0.f);
    float y1 = fmaxf((v11 - mean) * rs * gam[2 * lane + 1] + bet[2 * lane + 1], 0.f);
    int g = batch[n1];
    atomicAdd(&psum[g * 128 + 2 * lane], y0);
    atomicAdd(&psum[g * 128 + 2 * lane + 1], y1);
  }
}

// ---------------- MLP head (counts via binary search on sorted batch) ----------------
__global__ __launch_bounds__(128) void k_head(const float* __restrict__ psum,
    const int* __restrict__ batch, int N,
    const float* __restrict__ rW1, const float* __restrict__ rb1,
    const float* __restrict__ rg, const float* __restrict__ rbe,
    const float* __restrict__ rW2, const float* __restrict__ rb2,
    float* __restrict__ outp) {
  int g = blockIdx.x, t = threadIdx.x;
  __shared__ float pl[128];
  __shared__ float yv[32];
  __shared__ float rv[32];
  __shared__ float mv[2];
  __shared__ int scnt;
  if (t == 0) {
    int lo = 0, hi = N;
    while (lo < hi) { int mid = (lo + hi) >> 1; if (batch[mid] < g) lo = mid + 1; else hi = mid; }
    int lo2 = lo, hi2 = N;
    while (lo2 < hi2) { int mid = (lo2 + hi2) >> 1; if (batch[mid] < g + 1) lo2 = mid + 1; else hi2 = mid; }
    scnt = lo2 - lo;
  }
  __syncthreads();
  float cnt = fmaxf((float)scnt, 1.f);
  pl[t] = psum[g * 128 + t] / cnt;
  __syncthreads();
  if (t < 32) {
    float s = rb1[t];
    for (int c = 0; c < 128; c++) s += pl[c] * rW1[c * 32 + t];
    yv[t] = s;
  }
  __syncthreads();
  if (t == 0) {
    float s = 0.f, sq = 0.f;
    for (int j = 0; j < 32; j++) { s += yv[j]; sq += yv[j] * yv[j]; }
    float mean = s / 32.f;
    float var = sq / 32.f - mean * mean;
    mv[0] = mean; mv[1] = rsqrtf(var + 1e-5f);
  }
  __syncthreads();
  if (t < 32) {
    float y = (yv[t] - mv[0]) * mv[1] * rg[t] + rbe[t];
    rv[t] = fmaxf(y, 0.f);
  }
  __syncthreads();
  if (t < OUT_DIM) {
    float s = rb2[t];
    for (int j = 0; j < 32; j++) s += rv[j] * rW2[j * 8 + t];
    outp[g * 8 + t] = s;
  }
}

extern "C" void kernel_launch(void* const* d_in, const int* in_sizes, int n_in,
                              void* d_out, int out_size, void* d_ws, size_t ws_size,
                              hipStream_t stream) {
  const float* x    = (const float*)d_in[0];
  const int*   ei   = (const int*)d_in[1];
  const int*   batch= (const int*)d_in[3];
  const float* W1   = (const float*)d_in[4];
  const float* as1w = (const float*)d_in[5];
  const float* ad1w = (const float*)d_in[6];
  const float* b1   = (const float*)d_in[7];
  const float* g1   = (const float*)d_in[8];
  const float* be1  = (const float*)d_in[9];
  const float* W2   = (const float*)d_in[10];
  const float* as2w = (const float*)d_in[11];
  const float* ad2w = (const float*)d_in[12];
  const float* b2   = (const float*)d_in[13];
  const float* g2   = (const float*)d_in[14];
  const float* be2  = (const float*)d_in[15];
  const float* rW1  = (const float*)d_in[16];
  const float* rb1  = (const float*)d_in[17];
  const float* rg   = (const float*)d_in[18];
  const float* rbe  = (const float*)d_in[19];
  const float* rW2  = (const float*)d_in[20];
  const float* rb2  = (const float*)d_in[21];

  int N = in_sizes[0] / 128;
  int E = in_sizes[1] / 2;
  int ET = E + N;
  int nb = (N + 255) / 256;

  char* p = (char*)d_ws;
  u16* x_b   = (u16*)p; p += (size_t)N * 128 * 2;
  u16* aggx  = (u16*)p; p += (size_t)N * 512 * 2;
  u16* raw1  = (u16*)p; p += (size_t)N * 512 * 2;
  u16* h1_b  = (u16*)p; p += (size_t)N * 512 * 2;
  u16* raw2b = (u16*)p; p += (size_t)N * 128 * 2;
  u16* W1t   = (u16*)p; p += 512 * 128 * 2;
  u16* W2t   = (u16*)p; p += 128 * 512 * 2;
  float* ws  = (float*)p; p += 128 * 8 * 4;
  float* sa1 = (float*)p; p += (size_t)N * 4 * 4;
  float* da1 = (float*)p; p += (size_t)N * 4 * 4;
  float* sa2 = (float*)p; p += (size_t)N * 4;
  float* da2 = (float*)p; p += (size_t)N * 4;
  float* psum = (float*)p; p += GRAPHS * CH * 4;
  int* counts = (int*)p; p += (size_t)N * 4;
  int* indptr = (int*)p; p += (size_t)(N + 1) * 4;
  int* cursor = (int*)p; p += (size_t)N * 4;
  int* bsum   = (int*)p; p += (size_t)nb * 4;
  int* boff   = (int*)p; p += (size_t)nb * 4;
  int* srcs   = (int*)p; p += (size_t)ET * 4;

  hipMemsetAsync(counts, 0, (size_t)N * sizeof(int), stream);
  hipMemsetAsync(psum, 0, (size_t)GRAPHS * CH * sizeof(float), stream);

  int eb = (ET + 255) / 256;
  k_count<<<eb, 256, 0, stream>>>(ei, counts, E, N);
  k_scanA<<<nb, 256, 0, stream>>>(counts, bsum, N);
  k_scanB<<<1, 1024, 0, stream>>>(bsum, boff, nb);
  k_scanC<<<nb, 256, 0, stream>>>(counts, boff, indptr, cursor, N);
  k_scatter<<<eb, 256, 0, stream>>>(ei, cursor, srcs, E, N);

  // conversions + score matrices
  k_wt<<<(512 * 128 + 255) / 256, 256, 0, stream>>>(W1, W1t, 128, 512);
  k_wt<<<(512 * 128 + 255) / 256, 256, 0, stream>>>(W2, W2t, 512, 128);
  k_ws<<<1, 256, 0, stream>>>(W1, as1w, ad1w, ws);
  k_prep<<<(N + 3) / 4, 256, 0, stream>>>(x, ws, (u32*)x_b, (float4*)sa1, (float4*)da1, N);

  // conv1: aggregate x (2 nodes per wave), per-head GEMM (+bias), LN+ReLU
  k_aggx<<<(N + 7) / 8, 256, 0, stream>>>((const u32*)x_b, indptr, srcs,
                                          (const float4*)sa1, (const float4*)da1,
                                          (u32*)aggx, N);
  dim3 gridh((N + 127) / 128, 4);
  k_gemm_head<<<gridh, 256, 0, stream>>>(aggx, W1t, b1, raw1, N);
  k_ln512<<<(N + 3) / 4, 256, 0, stream>>>(raw1, g1, be1, h1_b, N);

  // conv2
  dim3 grid2((N + 127) / 128, 1);
  k_gemm_bf16<<<grid2, 256, 0, stream>>>(h1_b, W2t, raw2b, N, 128, 512);
  k_att_h1<<<(N + 3) / 4, 256, 0, stream>>>(raw2b, as2w, ad2w, sa2, da2, N);
  k_agg2f<<<(N + 7) / 8, 256, 0, stream>>>((const u32*)raw2b, indptr, srcs, sa2, da2,
                                           b2, g2, be2, batch, psum, N);

  // head (counts via binary search, no k_cnt)
  k_head<<<GRAPHS, 128, 0, stream>>>(psum, batch, N, rW1, rb1, rg, rbe, rW2, rb2,
                                     (float*)d_out);
}

// Round 9
// 358.249 us; speedup vs baseline: 1.3832x; 1.1495x over previous
//
#include <hip/hip_runtime.h>
#include <math.h>

#define HEADS 4
#define CH 128
#define HC 512
#define GRAPHS 128
#define OUT_DIM 8

typedef unsigned short u16;
typedef unsigned int u32;
typedef short short8 __attribute__((ext_vector_type(8)));
typedef float f32x4 __attribute__((ext_vector_type(4)));

__device__ inline u16 f2b(float f) {
  u32 u = __float_as_uint(f);
  u32 r = u + 0x7FFFu + ((u >> 16) & 1u);
  return (u16)(r >> 16);
}
__device__ inline float blo(u32 d) { return __uint_as_float(d << 16); }
__device__ inline float bhi(u32 d) { return __uint_as_float(d & 0xffff0000u); }
__device__ inline float lrelu(float v) { return v > 0.f ? v : 0.2f * v; }
// wave-uniform broadcast via v_readlane (SGPR index) — never ds_bpermute
__device__ inline int rdl(int v, int l) { return __builtin_amdgcn_readlane(v, l); }
__device__ inline float rdlf(float v, int l) {
  return __int_as_float(__builtin_amdgcn_readlane(__float_as_int(v), l));
}

// ---------------- CSR build ----------------
__global__ void k_count(const int* __restrict__ ei, int* __restrict__ counts, int E, int N) {
  int i = blockIdx.x * blockDim.x + threadIdx.x;
  int total = E + N;
  if (i >= total) return;
  int dst = (i < E) ? ei[E + i] : (i - E);
  atomicAdd(&counts[dst], 1);
}

__global__ __launch_bounds__(256) void k_scanA(const int* __restrict__ counts,
                                               int* __restrict__ bsum, int N) {
  __shared__ int sh[256];
  int b = blockIdx.x, t = threadIdx.x, i = b * 256 + t;
  sh[t] = (i < N) ? counts[i] : 0;
  __syncthreads();
  for (int off = 128; off; off >>= 1) {
    if (t < off) sh[t] += sh[t + off];
    __syncthreads();
  }
  if (t == 0) bsum[b] = sh[0];
}

__global__ __launch_bounds__(1024) void k_scanB(const int* __restrict__ bsum,
                                                int* __restrict__ boff, int nb) {
  __shared__ int sh[1024];
  int t = threadIdx.x;
  sh[t] = (t < nb) ? bsum[t] : 0;
  __syncthreads();
  for (int off = 1; off < 1024; off <<= 1) {
    int v = sh[t];
    int u = (t >= off) ? sh[t - off] : 0;
    __syncthreads();
    sh[t] = v + u;
    __syncthreads();
  }
  if (t < nb) boff[t] = (t == 0) ? 0 : sh[t - 1];
}

__global__ __launch_bounds__(256) void k_scanC(const int* __restrict__ counts,
                                               const int* __restrict__ boff,
                                               int* __restrict__ indptr,
                                               int* __restrict__ cursor, int N) {
  __shared__ int sh[256];
  int b = blockIdx.x, t = threadIdx.x, i = b * 256 + t;
  int v = (i < N) ? counts[i] : 0;
  sh[t] = v;
  __syncthreads();
  for (int off = 1; off < 256; off <<= 1) {
    int a = sh[t];
    int u = (t >= off) ? sh[t - off] : 0;
    __syncthreads();
    sh[t] = a + u;
    __syncthreads();
  }
  if (i < N) {
    int excl = boff[b] + sh[t] - v;
    indptr[i] = excl;
    cursor[i] = excl;
    if (i == N - 1) indptr[N] = excl + v;
  }
}

__global__ void k_scatter(const int* __restrict__ ei, int* __restrict__ cursor,
                          int* __restrict__ srcs, int E, int N) {
  int i = blockIdx.x * blockDim.x + threadIdx.x;
  int total = E + N;
  if (i >= total) return;
  int src, dst;
  if (i < E) { src = ei[i]; dst = ei[E + i]; } else { src = i - E; dst = i - E; }
  int pos = atomicAdd(&cursor[dst], 1);
  srcs[pos] = src;
}

// ---------------- converters ----------------
// W [K][Nc] fp32 -> Wt [Nc][K] bf16 (transposed)
__global__ void k_wt(const float* __restrict__ W, u16* __restrict__ Wt, int K, int Nc) {
  int i = blockIdx.x * blockDim.x + threadIdx.x;
  if (i >= K * Nc) return;
  int n = i / K, k = i - n * K;
  Wt[i] = f2b(W[(size_t)k * Nc + n]);
}

// ws[k][o]: o in 0..3 = src heads, 4..7 = dst heads.  ws = W1_head @ att_head
__global__ __launch_bounds__(256) void k_ws(const float* __restrict__ W1,
                                            const float* __restrict__ as1,
                                            const float* __restrict__ ad1,
                                            float* __restrict__ ws) {
  int t = threadIdx.x;
  #pragma unroll
  for (int r = 0; r < 4; r++) {
    int idx = r * 256 + t;       // 0..1023
    int k = idx >> 3, o = idx & 7, h = o & 3;
    const float* av = ((o < 4) ? as1 : ad1) + h * CH;
    const float* wrow = W1 + (size_t)k * HC + h * CH;
    float s = 0.f;
    for (int c = 0; c < CH; c++) s += wrow[c] * av[c];
    ws[idx] = s;
  }
}

// ---------------- fused x->bf16 conversion + conv1 scores (wave per node) ----------------
__global__ void k_prep(const float* __restrict__ x, const float* __restrict__ ws,
                       u32* __restrict__ xb, float4* __restrict__ sa1,
                       float4* __restrict__ da1, int N) {
  int n = blockIdx.x * (blockDim.x >> 6) + (threadIdx.x >> 6);
  int lane = threadIdx.x & 63;
  if (n >= N) return;
  float2 v = ((const float2*)(x + (size_t)n * 128))[lane];
  xb[(size_t)n * 64 + lane] = (u32)f2b(v.x) | ((u32)f2b(v.y) << 16);
  const float* w0 = ws + (2 * lane) * 8;
  const float* w1 = ws + (2 * lane + 1) * 8;
  float p[8];
  #pragma unroll
  for (int o = 0; o < 8; o++) p[o] = v.x * w0[o] + v.y * w1[o];
  #pragma unroll
  for (int off = 32; off; off >>= 1)
    #pragma unroll
    for (int o = 0; o < 8; o++) p[o] += __shfl_xor(p[o], off);
  if (lane == 0) {
    sa1[n] = make_float4(p[0], p[1], p[2], p[3]);
    da1[n] = make_float4(p[4], p[5], p[6], p[7]);
  }
}

// ---------------- conv1 aggregation over x (bf16), 4 heads ----------------
// Two nodes per wave interleaved; readlane broadcasts; unroll 4 (8 loads in flight).
__global__ __launch_bounds__(256) void k_aggx(
    const u32* __restrict__ xb, const int* __restrict__ indptr,
    const int* __restrict__ srcs, const float4* __restrict__ as1,
    const float4* __restrict__ ad1, u32* __restrict__ aggx, int N) {
  int t = threadIdx.x;
  int lane = t & 63, wid = t >> 6;
  int n0 = blockIdx.x * 8 + wid * 2;
  if (n0 >= N) return;
  int n1 = n0 + 1;
  bool has1 = n1 < N;
  int beg0 = indptr[n0], end0 = indptr[n0 + 1];
  int beg1 = end0, end1 = has1 ? indptr[n1 + 1] : end0;
  int deg0 = end0 - beg0, deg1 = end1 - beg1;
  float4 ad0 = ad1[n0];
  float4 adv1 = has1 ? ad1[n1] : make_float4(0.f, 0.f, 0.f, 0.f);

  if (deg0 <= 64 && deg1 <= 64) {
    int s0 = 0, s1 = 0;
    float w0[4] = {}, w1[4] = {};
    if (lane < deg0) {
      s0 = srcs[beg0 + lane];
      float4 a = as1[s0];
      w0[0] = __expf(lrelu(a.x + ad0.x)); w0[1] = __expf(lrelu(a.y + ad0.y));
      w0[2] = __expf(lrelu(a.z + ad0.z)); w0[3] = __expf(lrelu(a.w + ad0.w));
    }
    if (lane < deg1) {
      s1 = srcs[beg1 + lane];
      float4 a = as1[s1];
      w1[0] = __expf(lrelu(a.x + adv1.x)); w1[1] = __expf(lrelu(a.y + adv1.y));
      w1[2] = __expf(lrelu(a.z + adv1.z)); w1[3] = __expf(lrelu(a.w + adv1.w));
    }
    float e0[4] = {}, e1[4] = {};
    float c0[4][2] = {}, c1[4][2] = {};
    int dmax = deg0 > deg1 ? deg0 : deg1;
    int dpad = (dmax + 3) & ~3;
    for (int j = 0; j < dpad; j += 4) {
      u32 d[4], e[4];
      #pragma unroll
      for (int u = 0; u < 4; u++) d[u] = xb[(size_t)rdl(s0, j + u) * 64 + lane];
      #pragma unroll
      for (int u = 0; u < 4; u++) e[u] = xb[(size_t)rdl(s1, j + u) * 64 + lane];
      #pragma unroll
      for (int h = 0; h < 4; h++) {
        #pragma unroll
        for (int u = 0; u < 4; u++) {
          float a = rdlf(w0[h], j + u);
          e0[h] += a; c0[h][0] += a * blo(d[u]); c0[h][1] += a * bhi(d[u]);
          float b = rdlf(w1[h], j + u);
          e1[h] += b; c1[h][0] += b * blo(e[u]); c1[h][1] += b * bhi(e[u]);
        }
      }
    }
    {
      u32* orow = aggx + (size_t)n0 * 256;
      #pragma unroll
      for (int h = 0; h < 4; h++) {
        float iv = 1.f / (e0[h] + 1e-16f);
        orow[h * 64 + lane] = (u32)f2b(c0[h][0] * iv) | ((u32)f2b(c0[h][1] * iv) << 16);
      }
    }
    if (has1) {
      u32* orow = aggx + (size_t)n1 * 256;
      #pragma unroll
      for (int h = 0; h < 4; h++) {
        float iv = 1.f / (e1[h] + 1e-16f);
        orow[h * 64 + lane] = (u32)f2b(c1[h][0] * iv) | ((u32)f2b(c1[h][1] * iv) << 16);
      }
    }
    return;
  }
  // slow path (deg > 64): chunked, one node at a time
  for (int pass = 0; pass < 2; pass++) {
    if (pass == 1 && !has1) break;
    int n = pass ? n1 : n0;
    int beg = pass ? beg1 : beg0;
    int end = pass ? end1 : end0;
    float4 ad = pass ? adv1 : ad0;
    float e0[4] = {};
    float c0[4][2] = {};
    for (int base = beg; base < end; base += 64) {
      int cnt = min(64, end - base);
      int sreg = 0;
      float w0[4] = {};
      if (lane < cnt) {
        sreg = srcs[base + lane];
        float4 a = as1[sreg];
        w0[0] = __expf(lrelu(a.x + ad.x)); w0[1] = __expf(lrelu(a.y + ad.y));
        w0[2] = __expf(lrelu(a.z + ad.z)); w0[3] = __expf(lrelu(a.w + ad.w));
      }
      int cpad = (cnt + 1) & ~1;
      for (int j = 0; j < cpad; j += 2) {
        u32 dA = xb[(size_t)rdl(sreg, j) * 64 + lane];
        u32 dB = xb[(size_t)rdl(sreg, j + 1) * 64 + lane];
        float xA0 = blo(dA), xA1 = bhi(dA), xB0 = blo(dB), xB1 = bhi(dB);
        #pragma unroll
        for (int h = 0; h < 4; h++) {
          float a = rdlf(w0[h], j), b = rdlf(w0[h], j + 1);
          e0[h] += a + b;
          c0[h][0] += a * xA0 + b * xB0;
          c0[h][1] += a * xA1 + b * xB1;
        }
      }
    }
    u32* orow = aggx + (size_t)n * 256;
    #pragma unroll
    for (int h = 0; h < 4; h++) {
      float iv = 1.f / (e0[h] + 1e-16f);
      orow[h * 64 + lane] = (u32)f2b(c0[h][0] * iv) | ((u32)f2b(c0[h][1] * iv) << 16);
    }
  }
}

// ---------------- per-head GEMM: raw1[:, hC:(h+1)C] = aggx[:,h,:] @ W1[:,hC:(h+1)C] + b1 ----------------
__global__ __launch_bounds__(256) void k_gemm_head(
    const u16* __restrict__ A,    // aggx [M][512]
    const u16* __restrict__ Bt,   // W1t  [512][128]
    const float* __restrict__ bias,
    u16* __restrict__ C,          // raw1 [M][512]
    int M) {
  __shared__ u16 As[128 * 64];
  __shared__ u16 Bs[128 * 64];
  int t = threadIdx.x;
  int lane = t & 63, wid = t >> 6;
  int wr = wid >> 1, wc = wid & 1;
  int r0 = blockIdx.x * 128;
  int hh = blockIdx.y;
  const u16* Ah = A + hh * 128;
  const u16* Bh = Bt + (size_t)hh * 128 * 128;
  int lr = lane & 15, lk = lane >> 4;
  f32x4 acc[4][4] = {};
  for (int kt = 0; kt < 128; kt += 64) {
    #pragma unroll
    for (int it = 0; it < 4; it++) {
      int q = wid * 4096 + it * 1024 + lane * 16;
      int row = q >> 7;
      int soff = ((q >> 4) & 7) ^ (row & 7);
      {
        int gr = r0 + row; if (gr >= M) gr = M - 1;
        const u16* gp = Ah + (size_t)gr * 512 + kt + soff * 8;
        __builtin_amdgcn_global_load_lds(
            (const __attribute__((address_space(1))) void*)gp,
            (__attribute__((address_space(3))) void*)((char*)As + wid * 4096 + it * 1024),
            16, 0, 0);
      }
      {
        const u16* gp = Bh + (size_t)row * 128 + kt + soff * 8;
        __builtin_amdgcn_global_load_lds(
            (const __attribute__((address_space(1))) void*)gp,
            (__attribute__((address_space(3))) void*)((char*)Bs + wid * 4096 + it * 1024),
            16, 0, 0);
      }
    }
    __syncthreads();
    const char* Ab = (const char*)As;
    const char* Bb = (const char*)Bs;
    #pragma unroll
    for (int kk = 0; kk < 2; kk++) {
      short8 a[4], b[4];
      #pragma unroll
      for (int m = 0; m < 4; m++) {
        int row = wr * 64 + m * 16 + lr;
        int off = (row << 7) + kk * 64 + lk * 16;
        off ^= (row & 7) << 4;
        a[m] = *(const short8*)(Ab + off);
      }
      #pragma unroll
      for (int nn = 0; nn < 4; nn++) {
        int row = wc * 64 + nn * 16 + lr;
        int off = (row << 7) + kk * 64 + lk * 16;
        off ^= (row & 7) << 4;
        b[nn] = *(const short8*)(Bb + off);
      }
      #pragma unroll
      for (int m = 0; m < 4; m++)
        #pragma unroll
        for (int nn = 0; nn < 4; nn++)
          acc[m][nn] = __builtin_amdgcn_mfma_f32_16x16x32_bf16(a[m], b[nn], acc[m][nn], 0, 0, 0);
    }
    __syncthreads();
  }
  #pragma unroll
  for (int m = 0; m < 4; m++)
    #pragma unroll
    for (int nn = 0; nn < 4; nn++)
      #pragma unroll
      for (int r = 0; r < 4; r++) {
        int row = r0 + wr * 64 + m * 16 + lk * 4 + r;
        if (row < M) {
          int gcol = hh * 128 + wc * 64 + nn * 16 + lr;
          C[(size_t)row * 512 + gcol] = f2b(acc[m][nn][r] + bias[gcol]);
        }
      }
}

// ---------------- LN+ReLU over 512 channels (bf16 in/out) ----------------
__global__ __launch_bounds__(256) void k_ln512(const u16* __restrict__ raw,
                                               const float* __restrict__ gam,
                                               const float* __restrict__ bet,
                                               u16* __restrict__ out, int N) {
  int n = blockIdx.x * 4 + (threadIdx.x >> 6);
  int lane = threadIdx.x & 63;
  if (n >= N) return;
  const uint4* r = (const uint4*)(raw + (size_t)n * 512);
  uint4 q = r[lane];
  float v[8];
  v[0] = blo(q.x); v[1] = bhi(q.x); v[2] = blo(q.y); v[3] = bhi(q.y);
  v[4] = blo(q.z); v[5] = bhi(q.z); v[6] = blo(q.w); v[7] = bhi(q.w);
  float s1 = 0.f, s2 = 0.f;
  #pragma unroll
  for (int j = 0; j < 8; j++) { s1 += v[j]; s2 += v[j] * v[j]; }
  #pragma unroll
  for (int off = 32; off; off >>= 1) {
    s1 += __shfl_xor(s1, off);
    s2 += __shfl_xor(s2, off);
  }
  float mean = s1 * (1.f / 512.f);
  float var = s2 * (1.f / 512.f) - mean * mean;
  float rs = rsqrtf(var + 1e-5f);
  u32 o[4];
  #pragma unroll
  for (int j = 0; j < 4; j++) {
    int ch = lane * 8 + 2 * j;
    float y0 = fmaxf((v[2 * j] - mean) * rs * gam[ch] + bet[ch], 0.f);
    float y1 = fmaxf((v[2 * j + 1] - mean) * rs * gam[ch + 1] + bet[ch + 1], 0.f);
    o[j] = (u32)f2b(y0) | ((u32)f2b(y1) << 16);
  }
  ((uint4*)(out + (size_t)n * 512))[lane] = make_uint4(o[0], o[1], o[2], o[3]);
}

// ---------------- bf16 MFMA GEMM (conv2): C[M][128] = A[M][512] * Bt[128][512]^T ----------------
__global__ __launch_bounds__(256) void k_gemm_bf16(
    const u16* __restrict__ A, const u16* __restrict__ Bt,
    u16* __restrict__ C, int M, int Nc, int K) {
  __shared__ u16 As[128 * 64];
  __shared__ u16 Bs[128 * 64];
  int t = threadIdx.x;
  int lane = t & 63, wid = t >> 6;
  int wr = wid >> 1, wc = wid & 1;
  int r0 = blockIdx.x * 128, c0 = blockIdx.y * 128;
  int lr = lane & 15, lk = lane >> 4;
  f32x4 acc[4][4] = {};
  for (int kt = 0; kt < K; kt += 64) {
    #pragma unroll
    for (int it = 0; it < 4; it++) {
      int q = wid * 4096 + it * 1024 + lane * 16;
      int row = q >> 7;
      int soff = ((q >> 4) & 7) ^ (row & 7);
      {
        int gr = r0 + row; if (gr >= M) gr = M - 1;
        const u16* gp = A + (size_t)gr * K + kt + soff * 8;
        __builtin_amdgcn_global_load_lds(
            (const __attribute__((address_space(1))) void*)gp,
            (__attribute__((address_space(3))) void*)((char*)As + wid * 4096 + it * 1024),
            16, 0, 0);
      }
      {
        int gn = c0 + row;
        const u16* gp = Bt + (size_t)gn * K + kt + soff * 8;
        __builtin_amdgcn_global_load_lds(
            (const __attribute__((address_space(1))) void*)gp,
            (__attribute__((address_space(3))) void*)((char*)Bs + wid * 4096 + it * 1024),
            16, 0, 0);
      }
    }
    __syncthreads();
    const char* Ab = (const char*)As;
    const char* Bb = (const char*)Bs;
    #pragma unroll
    for (int kk = 0; kk < 2; kk++) {
      short8 a[4], b[4];
      #pragma unroll
      for (int m = 0; m < 4; m++) {
        int row = wr * 64 + m * 16 + lr;
        int off = (row << 7) + kk * 64 + lk * 16;
        off ^= (row & 7) << 4;
        a[m] = *(const short8*)(Ab + off);
      }
      #pragma unroll
      for (int nn = 0; nn < 4; nn++) {
        int row = wc * 64 + nn * 16 + lr;
        int off = (row << 7) + kk * 64 + lk * 16;
        off ^= (row & 7) << 4;
        b[nn] = *(const short8*)(Bb + off);
      }
      #pragma unroll
      for (int m = 0; m < 4; m++)
        #pragma unroll
        for (int nn = 0; nn < 4; nn++)
          acc[m][nn] = __builtin_amdgcn_mfma_f32_16x16x32_bf16(a[m], b[nn], acc[m][nn], 0, 0, 0);
    }
    __syncthreads();
  }
  #pragma unroll
  for (int m = 0; m < 4; m++)
    #pragma unroll
    for (int nn = 0; nn < 4; nn++)
      #pragma unroll
      for (int r = 0; r < 4; r++) {
        int row = r0 + wr * 64 + m * 16 + lk * 4 + r;
        if (row < M) {
          int col = c0 + wc * 64 + nn * 16 + lr;
          C[(size_t)row * Nc + col] = f2b(acc[m][nn][r]);
        }
      }
}

// ---------------- conv2 scores ----------------
__global__ void k_att_h1(const u16* __restrict__ hm, const float* __restrict__ att_s,
                         const float* __restrict__ att_d, float* __restrict__ s_out,
                         float* __restrict__ d_out, int N) {
  int n = blockIdx.x * (blockDim.x >> 6) + (threadIdx.x >> 6);
  int lane = threadIdx.x & 63;
  if (n >= N) return;
  const u32* row = (const u32*)(hm + (size_t)n * CH);
  u32 d = row[lane];
  float x0 = blo(d), x1 = bhi(d);
  float ps = x0 * att_s[2 * lane] + x1 * att_s[2 * lane + 1];
  float pd = x0 * att_d[2 * lane] + x1 * att_d[2 * lane + 1];
  #pragma unroll
  for (int off = 32; off; off >>= 1) {
    ps += __shfl_xor(ps, off);
    pd += __shfl_xor(pd, off);
  }
  if (lane == 0) { s_out[n] = ps; d_out[n] = pd; }
}

// ---------------- conv2 aggregation + bias + LN + ReLU -> h2 (fp32), no atomics ----------------
// Two nodes per wave interleaved; readlane broadcasts; unroll 8 (16 loads in flight).
__global__ __launch_bounds__(256) void k_agg2f(
    const u32* __restrict__ raw2, const int* __restrict__ indptr,
    const int* __restrict__ srcs, const float* __restrict__ as2,
    const float* __restrict__ ad2, const float* __restrict__ bias,
    const float* __restrict__ gam, const float* __restrict__ bet,
    float* __restrict__ h2, int N) {
  int t = threadIdx.x;
  int lane = t & 63, wid = t >> 6;
  int n0 = blockIdx.x * 8 + wid * 2;
  if (n0 >= N) return;
  int n1 = n0 + 1;
  bool has1 = n1 < N;
  int beg0 = indptr[n0], end0 = indptr[n0 + 1];
  int beg1 = end0, end1 = has1 ? indptr[n1 + 1] : end0;
  int deg0 = end0 - beg0, deg1 = end1 - beg1;
  float adv0 = ad2[n0];
  float adv1 = has1 ? ad2[n1] : 0.f;
  float ds0 = 0.f, ds1 = 0.f;
  float a00 = 0.f, a01 = 0.f, a10 = 0.f, a11 = 0.f;

  if (deg0 <= 64 && deg1 <= 64) {
    int s0 = 0, s1r = 0;
    float w0 = 0.f, w1 = 0.f;
    if (lane < deg0) { s0 = srcs[beg0 + lane]; w0 = __expf(lrelu(as2[s0] + adv0)); }
    if (lane < deg1) { s1r = srcs[beg1 + lane]; w1 = __expf(lrelu(as2[s1r] + adv1)); }
    int dmax = deg0 > deg1 ? deg0 : deg1;
    int dpad = (dmax + 7) & ~7;
    for (int j = 0; j < dpad; j += 8) {
      u32 d[8], e[8];
      #pragma unroll
      for (int u = 0; u < 8; u++) d[u] = raw2[(size_t)rdl(s0, j + u) * 64 + lane];
      #pragma unroll
      for (int u = 0; u < 8; u++) e[u] = raw2[(size_t)rdl(s1r, j + u) * 64 + lane];
      #pragma unroll
      for (int u = 0; u < 8; u++) {
        float a = rdlf(w0, j + u);
        ds0 += a; a00 += a * blo(d[u]); a01 += a * bhi(d[u]);
        float b = rdlf(w1, j + u);
        ds1 += b; a10 += b * blo(e[u]); a11 += b * bhi(e[u]);
      }
    }
  } else {
    // slow path: chunked, node0 then node1
    for (int pass = 0; pass < 2; pass++) {
      if (pass == 1 && !has1) break;
      int beg = pass ? beg1 : beg0;
      int end = pass ? end1 : end0;
      float adv = pass ? adv1 : adv0;
      for (int base = beg; base < end; base += 64) {
        int cnt = min(64, end - base);
        int sreg = 0;
        float w = 0.f;
        if (lane < cnt) { sreg = srcs[base + lane]; w = __expf(lrelu(as2[sreg] + adv)); }
        int cpad = (cnt + 3) & ~3;
        for (int j = 0; j < cpad; j += 4) {
          u32 dA = raw2[(size_t)rdl(sreg, j) * 64 + lane];
          u32 dB = raw2[(size_t)rdl(sreg, j + 1) * 64 + lane];
          u32 dC = raw2[(size_t)rdl(sreg, j + 2) * 64 + lane];
          u32 dD = raw2[(size_t)rdl(sreg, j + 3) * 64 + lane];
          float wA = rdlf(w, j), wB = rdlf(w, j + 1);
          float wC = rdlf(w, j + 2), wD = rdlf(w, j + 3);
          float lo = wA * blo(dA) + wB * blo(dB) + wC * blo(dC) + wD * blo(dD);
          float hi = wA * bhi(dA) + wB * bhi(dB) + wC * bhi(dC) + wD * bhi(dD);
          float sw = (wA + wB) + (wC + wD);
          if (pass) { ds1 += sw; a10 += lo; a11 += hi; }
          else      { ds0 += sw; a00 += lo; a01 += hi; }
        }
      }
    }
  }

  // LN + ReLU, both nodes (butterflies interleaved), write h2 rows
  float inv0 = 1.f / (ds0 + 1e-16f);
  float v00 = a00 * inv0 + bias[2 * lane];
  float v01 = a01 * inv0 + bias[2 * lane + 1];
  float s1a = v00 + v01, s2a = v00 * v00 + v01 * v01;
  float inv1 = 1.f / (ds1 + 1e-16f);
  float v10 = a10 * inv1 + bias[2 * lane];
  float v11 = a11 * inv1 + bias[2 * lane + 1];
  float s1b = v10 + v11, s2b = v10 * v10 + v11 * v11;
  #pragma unroll
  for (int off = 32; off; off >>= 1) {
    s1a += __shfl_xor(s1a, off);
    s2a += __shfl_xor(s2a, off);
    s1b += __shfl_xor(s1b, off);
    s2b += __shfl_xor(s2b, off);
  }
  {
    float mean = s1a * (1.f / 128.f);
    float var = s2a * (1.f / 128.f) - mean * mean;
    float rs = rsqrtf(var + 1e-5f);
    float y0 = fmaxf((v00 - mean) * rs * gam[2 * lane] + bet[2 * lane], 0.f);
    float y1 = fmaxf((v01 - mean) * rs * gam[2 * lane + 1] + bet[2 * lane + 1], 0.f);
    ((float2*)(h2 + (size_t)n0 * 128))[lane] = make_float2(y0, y1);
  }
  if (has1) {
    float mean = s1b * (1.f / 128.f);
    float var = s2b * (1.f / 128.f) - mean * mean;
    float rs = rsqrtf(var + 1e-5f);
    float y0 = fmaxf((v10 - mean) * rs * gam[2 * lane] + bet[2 * lane], 0.f);
    float y1 = fmaxf((v11 - mean) * rs * gam[2 * lane + 1] + bet[2 * lane + 1], 0.f);
    ((float2*)(h2 + (size_t)n1 * 128))[lane] = make_float2(y0, y1);
  }
}

// ---------------- MLP head with segment-sum pooling (batch is sorted; no atomics) ----------------
__global__ __launch_bounds__(256) void k_head(const float* __restrict__ h2,
    const int* __restrict__ batch, int N,
    const float* __restrict__ rW1, const float* __restrict__ rb1,
    const float* __restrict__ rg, const float* __restrict__ rbe,
    const float* __restrict__ rW2, const float* __restrict__ rb2,
    float* __restrict__ outp) {
  int g = blockIdx.x, t = threadIdx.x;
  int ch = t & 127, half = t >> 7;
  __shared__ float part[2][128];
  __shared__ float pl[128];
  __shared__ float yv[32];
  __shared__ float rv[32];
  __shared__ float mv[2];
  __shared__ int sseg[2];
  if (t == 0) {
    int lo = 0, hi = N;
    while (lo < hi) { int mid = (lo + hi) >> 1; if (batch[mid] < g) lo = mid + 1; else hi = mid; }
    int lo2 = lo, hi2 = N;
    while (lo2 < hi2) { int mid = (lo2 + hi2) >> 1; if (batch[mid] < g + 1) lo2 = mid + 1; else hi2 = mid; }
    sseg[0] = lo; sseg[1] = lo2;
  }
  __syncthreads();
  int lo = sseg[0], hi = sseg[1];
  float s = 0.f;
  int n = lo + half;
  for (; n + 8 <= hi; n += 8) {
    s += h2[(size_t)n * 128 + ch] + h2[(size_t)(n + 2) * 128 + ch]
       + h2[(size_t)(n + 4) * 128 + ch] + h2[(size_t)(n + 6) * 128 + ch];
  }
  for (; n < hi; n += 2) s += h2[(size_t)n * 128 + ch];
  part[half][ch] = s;
  __syncthreads();
  float cnt = fmaxf((float)(hi - lo), 1.f);
  if (t < 128) pl[t] = (part[0][t] + part[1][t]) / cnt;
  __syncthreads();
  if (t < 32) {
    float sum = rb1[t];
    for (int c = 0; c < 128; c++) sum += pl[c] * rW1[c * 32 + t];
    yv[t] = sum;
  }
  __syncthreads();
  if (t == 0) {
    float sm = 0.f, sq = 0.f;
    for (int j = 0; j < 32; j++) { sm += yv[j]; sq += yv[j] * yv[j]; }
    float mean = sm / 32.f;
    float var = sq / 32.f - mean * mean;
    mv[0] = mean; mv[1] = rsqrtf(var + 1e-5f);
  }
  __syncthreads();
  if (t < 32) {
    float y = (yv[t] - mv[0]) * mv[1] * rg[t] + rbe[t];
    rv[t] = fmaxf(y, 0.f);
  }
  __syncthreads();
  if (t < OUT_DIM) {
    float sum = rb2[t];
    for (int j = 0; j < 32; j++) sum += rv[j] * rW2[j * 8 + t];
    outp[g * 8 + t] = sum;
  }
}

extern "C" void kernel_launch(void* const* d_in, const int* in_sizes, int n_in,
                              void* d_out, int out_size, void* d_ws, size_t ws_size,
                              hipStream_t stream) {
  const float* x    = (const float*)d_in[0];
  const int*   ei   = (const int*)d_in[1];
  const int*   batch= (const int*)d_in[3];
  const float* W1   = (const float*)d_in[4];
  const float* as1w = (const float*)d_in[5];
  const float* ad1w = (const float*)d_in[6];
  const float* b1   = (const float*)d_in[7];
  const float* g1   = (const float*)d_in[8];
  const float* be1  = (const float*)d_in[9];
  const float* W2   = (const float*)d_in[10];
  const float* as2w = (const float*)d_in[11];
  const float* ad2w = (const float*)d_in[12];
  const float* b2   = (const float*)d_in[13];
  const float* g2   = (const float*)d_in[14];
  const float* be2  = (const float*)d_in[15];
  const float* rW1  = (const float*)d_in[16];
  const float* rb1  = (const float*)d_in[17];
  const float* rg   = (const float*)d_in[18];
  const float* rbe  = (const float*)d_in[19];
  const float* rW2  = (const float*)d_in[20];
  const float* rb2  = (const float*)d_in[21];

  int N = in_sizes[0] / 128;
  int E = in_sizes[1] / 2;
  int ET = E + N;
  int nb = (N + 255) / 256;

  char* p = (char*)d_ws;
  u16* x_b   = (u16*)p; p += (size_t)N * 128 * 2;
  u16* aggx  = (u16*)p; p += (size_t)N * 512 * 2;
  u16* raw1  = (u16*)p; p += (size_t)N * 512 * 2;
  u16* h1_b  = (u16*)p; p += (size_t)N * 512 * 2;
  u16* raw2b = (u16*)p; p += (size_t)N * 128 * 2;
  float* h2  = (float*)p; p += (size_t)N * 128 * 4;
  u16* W1t   = (u16*)p; p += 512 * 128 * 2;
  u16* W2t   = (u16*)p; p += 128 * 512 * 2;
  float* ws  = (float*)p; p += 128 * 8 * 4;
  float* sa1 = (float*)p; p += (size_t)N * 4 * 4;
  float* da1 = (float*)p; p += (size_t)N * 4 * 4;
  float* sa2 = (float*)p; p += (size_t)N * 4;
  float* da2 = (float*)p; p += (size_t)N * 4;
  int* counts = (int*)p; p += (size_t)N * 4;
  int* indptr = (int*)p; p += (size_t)(N + 1) * 4;
  int* cursor = (int*)p; p += (size_t)N * 4;
  int* bsum   = (int*)p; p += (size_t)nb * 4;
  int* boff   = (int*)p; p += (size_t)nb * 4;
  int* srcs   = (int*)p; p += (size_t)ET * 4;

  hipMemsetAsync(counts, 0, (size_t)N * sizeof(int), stream);

  int eb = (ET + 255) / 256;
  k_count<<<eb, 256, 0, stream>>>(ei, counts, E, N);
  k_scanA<<<nb, 256, 0, stream>>>(counts, bsum, N);
  k_scanB<<<1, 1024, 0, stream>>>(bsum, boff, nb);
  k_scanC<<<nb, 256, 0, stream>>>(counts, boff, indptr, cursor, N);
  k_scatter<<<eb, 256, 0, stream>>>(ei, cursor, srcs, E, N);

  // conversions + score matrices
  k_wt<<<(512 * 128 + 255) / 256, 256, 0, stream>>>(W1, W1t, 128, 512);
  k_wt<<<(512 * 128 + 255) / 256, 256, 0, stream>>>(W2, W2t, 512, 128);
  k_ws<<<1, 256, 0, stream>>>(W1, as1w, ad1w, ws);
  k_prep<<<(N + 3) / 4, 256, 0, stream>>>(x, ws, (u32*)x_b, (float4*)sa1, (float4*)da1, N);

  // conv1: aggregate x (2 nodes per wave), per-head GEMM (+bias), LN+ReLU
  k_aggx<<<(N + 7) / 8, 256, 0, stream>>>((const u32*)x_b, indptr, srcs,
                                          (const float4*)sa1, (const float4*)da1,
                                          (u32*)aggx, N);
  dim3 gridh((N + 127) / 128, 4);
  k_gemm_head<<<gridh, 256, 0, stream>>>(aggx, W1t, b1, raw1, N);
  k_ln512<<<(N + 3) / 4, 256, 0, stream>>>(raw1, g1, be1, h1_b, N);

  // conv2
  dim3 grid2((N + 127) / 128, 1);
  k_gemm_bf16<<<grid2, 256, 0, stream>>>(h1_b, W2t, raw2b, N, 128, 512);
  k_att_h1<<<(N + 3) / 4, 256, 0, stream>>>(raw2b, as2w, ad2w, sa2, da2, N);
  k_agg2f<<<(N + 7) / 8, 256, 0, stream>>>((const u32*)raw2b, indptr, srcs, sa2, da2,
                                           b2, g2, be2, h2, N);

  // head: segment-sum pooling (batch sorted) + MLP
  k_head<<<GRAPHS, 256, 0, stream>>>(h2, batch, N, rW1, rb1, rg, rbe, rW2, rb2,
                                     (float*)d_out);
}

// Round 10
// 324.656 us; speedup vs baseline: 1.5264x; 1.1035x over previous
//
#include <hip/hip_runtime.h>
#include <math.h>

#define HEADS 4
#define CH 128
#define HC 512
#define GRAPHS 128
#define OUT_DIM 8

typedef unsigned short u16;
typedef unsigned int u32;
typedef short short8 __attribute__((ext_vector_type(8)));
typedef float f32x4 __attribute__((ext_vector_type(4)));
typedef float f32x2 __attribute__((ext_vector_type(2)));

__device__ inline u16 f2b(float f) {
  u32 u = __float_as_uint(f);
  u32 r = u + 0x7FFFu + ((u >> 16) & 1u);
  return (u16)(r >> 16);
}
__device__ inline float blo(u32 d) { return __uint_as_float(d << 16); }
__device__ inline float bhi(u32 d) { return __uint_as_float(d & 0xffff0000u); }
__device__ inline f32x2 bunpack(u32 d) {
  f32x2 r; r.x = blo(d); r.y = bhi(d); return r;
}
__device__ inline float lrelu(float v) { return v > 0.f ? v : 0.2f * v; }
// wave-uniform broadcast via v_readlane (SGPR result) — never ds_bpermute
__device__ inline int rdl(int v, int l) { return __builtin_amdgcn_readlane(v, l); }
__device__ inline float rdlf(float v, int l) {
  return __int_as_float(__builtin_amdgcn_readlane(__float_as_int(v), l));
}

// ---------------- CSR build ----------------
__global__ __launch_bounds__(256) void k_scanA(const int* __restrict__ counts,
                                               int* __restrict__ bsum, int N) {
  __shared__ int sh[256];
  int b = blockIdx.x, t = threadIdx.x, i = b * 256 + t;
  sh[t] = (i < N) ? counts[i] : 0;
  __syncthreads();
  for (int off = 128; off; off >>= 1) {
    if (t < off) sh[t] += sh[t + off];
    __syncthreads();
  }
  if (t == 0) bsum[b] = sh[0];
}

__global__ __launch_bounds__(1024) void k_scanB(const int* __restrict__ bsum,
                                                int* __restrict__ boff, int nb) {
  __shared__ int sh[1024];
  int t = threadIdx.x;
  sh[t] = (t < nb) ? bsum[t] : 0;
  __syncthreads();
  for (int off = 1; off < 1024; off <<= 1) {
    int v = sh[t];
    int u = (t >= off) ? sh[t - off] : 0;
    __syncthreads();
    sh[t] = v + u;
    __syncthreads();
  }
  if (t < nb) boff[t] = (t == 0) ? 0 : sh[t - 1];
}

__global__ __launch_bounds__(256) void k_scanC(const int* __restrict__ counts,
                                               const int* __restrict__ boff,
                                               int* __restrict__ indptr,
                                               int* __restrict__ cursor, int N) {
  __shared__ int sh[256];
  int b = blockIdx.x, t = threadIdx.x, i = b * 256 + t;
  int v = (i < N) ? counts[i] : 0;
  sh[t] = v;
  __syncthreads();
  for (int off = 1; off < 256; off <<= 1) {
    int a = sh[t];
    int u = (t >= off) ? sh[t - off] : 0;
    __syncthreads();
    sh[t] = a + u;
    __syncthreads();
  }
  if (i < N) {
    int excl = boff[b] + sh[t] - v;
    indptr[i] = excl;
    cursor[i] = excl;
    if (i == N - 1) indptr[N] = excl + v;
  }
}

__global__ void k_scatter(const int* __restrict__ ei, int* __restrict__ cursor,
                          int* __restrict__ srcs, int E, int N) {
  int i = blockIdx.x * blockDim.x + threadIdx.x;
  int total = E + N;
  if (i >= total) return;
  int src, dst;
  if (i < E) { src = ei[i]; dst = ei[E + i]; } else { src = i - E; dst = i - E; }
  int pos = atomicAdd(&cursor[dst], 1);
  srcs[pos] = src;
}

// ---------------- merged weight prep: W1t, W2t, ws ----------------
// blocks [0,256): W1t;  [256,512): W2t;  [512,516): ws
__global__ __launch_bounds__(256) void k_wprep(const float* __restrict__ W1,
                                               const float* __restrict__ W2,
                                               const float* __restrict__ as1,
                                               const float* __restrict__ ad1,
                                               u16* __restrict__ W1t,
                                               u16* __restrict__ W2t,
                                               float* __restrict__ ws) {
  int b = blockIdx.x, t = threadIdx.x;
  if (b < 256) {
    int i = b * 256 + t;               // Wt index over [512][128]
    int n = i >> 7, k = i & 127;
    W1t[i] = f2b(W1[(size_t)k * HC + n]);
  } else if (b < 512) {
    int i = (b - 256) * 256 + t;       // Wt index over [128][512]
    int n = i >> 9, k = i & 511;
    W2t[i] = f2b(W2[(size_t)k * CH + n]);
  } else {
    int idx = (b - 512) * 256 + t;     // 0..1023
    int k = idx >> 3, o = idx & 7, h = o & 3;
    const float* av = ((o < 4) ? as1 : ad1) + h * CH;
    const float* wrow = W1 + (size_t)k * HC + h * CH;
    float s = 0.f;
    for (int c = 0; c < CH; c++) s += wrow[c] * av[c];
    ws[idx] = s;
  }
}

// ---------------- merged: edge-count atomics + x->bf16 + conv1 scores ----------------
__global__ void k_count_prep(const int* __restrict__ ei, int* __restrict__ counts,
                             int E, int N, int eb,
                             const float* __restrict__ x, const float* __restrict__ ws,
                             u32* __restrict__ xb, float4* __restrict__ sa1,
                             float4* __restrict__ da1) {
  if ((int)blockIdx.x < eb) {
    int i = blockIdx.x * 256 + threadIdx.x;
    int total = E + N;
    if (i >= total) return;
    int dst = (i < E) ? ei[E + i] : (i - E);
    atomicAdd(&counts[dst], 1);
    return;
  }
  int n = (blockIdx.x - eb) * 4 + (threadIdx.x >> 6);
  int lane = threadIdx.x & 63;
  if (n >= N) return;
  float2 v = ((const float2*)(x + (size_t)n * 128))[lane];
  xb[(size_t)n * 64 + lane] = (u32)f2b(v.x) | ((u32)f2b(v.y) << 16);
  const float* w0 = ws + (2 * lane) * 8;
  const float* w1 = ws + (2 * lane + 1) * 8;
  float p[8];
  #pragma unroll
  for (int o = 0; o < 8; o++) p[o] = v.x * w0[o] + v.y * w1[o];
  #pragma unroll
  for (int off = 32; off; off >>= 1)
    #pragma unroll
    for (int o = 0; o < 8; o++) p[o] += __shfl_xor(p[o], off);
  if (lane == 0) {
    sa1[n] = make_float4(p[0], p[1], p[2], p[3]);
    da1[n] = make_float4(p[4], p[5], p[6], p[7]);
  }
}

// ---------------- conv1 aggregation over x (bf16), 4 heads ----------------
// Two nodes per wave; readlane broadcasts; pk_fma accumulators; tail-split.
__global__ __launch_bounds__(256) void k_aggx(
    const u32* __restrict__ xb, const int* __restrict__ indptr,
    const int* __restrict__ srcs, const float4* __restrict__ as1,
    const float4* __restrict__ ad1, u32* __restrict__ aggx, int N) {
  int t = threadIdx.x;
  int lane = t & 63, wid = t >> 6;
  int n0 = blockIdx.x * 8 + wid * 2;
  if (n0 >= N) return;
  int n1 = n0 + 1;
  bool has1 = n1 < N;
  int beg0 = indptr[n0], end0 = indptr[n0 + 1];
  int beg1 = end0, end1 = has1 ? indptr[n1 + 1] : end0;
  int deg0 = end0 - beg0, deg1 = end1 - beg1;
  float4 ad0 = ad1[n0];
  float4 adv1 = has1 ? ad1[n1] : make_float4(0.f, 0.f, 0.f, 0.f);

  if (deg0 <= 64 && deg1 <= 64) {
    int s0 = 0, s1 = 0;
    float w0[4] = {}, w1[4] = {};
    if (lane < deg0) {
      s0 = srcs[beg0 + lane];
      float4 a = as1[s0];
      w0[0] = __expf(lrelu(a.x + ad0.x)); w0[1] = __expf(lrelu(a.y + ad0.y));
      w0[2] = __expf(lrelu(a.z + ad0.z)); w0[3] = __expf(lrelu(a.w + ad0.w));
    }
    if (lane < deg1) {
      s1 = srcs[beg1 + lane];
      float4 a = as1[s1];
      w1[0] = __expf(lrelu(a.x + adv1.x)); w1[1] = __expf(lrelu(a.y + adv1.y));
      w1[2] = __expf(lrelu(a.z + adv1.z)); w1[3] = __expf(lrelu(a.w + adv1.w));
    }
    f32x2 c0[4] = {}, c1[4] = {};
    int dboth = (deg0 < deg1 ? deg0 : deg1) & ~3;
    int j = 0;
    for (; j < dboth; j += 4) {
      u32 d[4], e[4];
      #pragma unroll
      for (int u = 0; u < 4; u++) d[u] = xb[(size_t)rdl(s0, j + u) * 64 + lane];
      #pragma unroll
      for (int u = 0; u < 4; u++) e[u] = xb[(size_t)rdl(s1, j + u) * 64 + lane];
      #pragma unroll
      for (int u = 0; u < 4; u++) {
        f32x2 xv = bunpack(d[u]);
        f32x2 yv = bunpack(e[u]);
        #pragma unroll
        for (int h = 0; h < 4; h++) {
          c0[h] += xv * rdlf(w0[h], j + u);
          c1[h] += yv * rdlf(w1[h], j + u);
        }
      }
    }
    int pad0 = (deg0 + 3) & ~3;
    for (int ja = j; ja < pad0; ja += 4) {
      u32 d[4];
      #pragma unroll
      for (int u = 0; u < 4; u++) d[u] = xb[(size_t)rdl(s0, ja + u) * 64 + lane];
      #pragma unroll
      for (int u = 0; u < 4; u++) {
        f32x2 xv = bunpack(d[u]);
        #pragma unroll
        for (int h = 0; h < 4; h++) c0[h] += xv * rdlf(w0[h], ja + u);
      }
    }
    int pad1 = (deg1 + 3) & ~3;
    for (int jb = j; jb < pad1; jb += 4) {
      u32 e[4];
      #pragma unroll
      for (int u = 0; u < 4; u++) e[u] = xb[(size_t)rdl(s1, jb + u) * 64 + lane];
      #pragma unroll
      for (int u = 0; u < 4; u++) {
        f32x2 yv = bunpack(e[u]);
        #pragma unroll
        for (int h = 0; h < 4; h++) c1[h] += yv * rdlf(w1[h], jb + u);
      }
    }
    // denominators via butterflies (DS pipe, off the VALU critical path)
    float e0[4], e1[4];
    #pragma unroll
    for (int h = 0; h < 4; h++) {
      float v0 = w0[h], v1 = w1[h];
      #pragma unroll
      for (int off = 32; off; off >>= 1) {
        v0 += __shfl_xor(v0, off);
        v1 += __shfl_xor(v1, off);
      }
      e0[h] = v0; e1[h] = v1;
    }
    {
      u32* orow = aggx + (size_t)n0 * 256;
      #pragma unroll
      for (int h = 0; h < 4; h++) {
        float iv = 1.f / (e0[h] + 1e-16f);
        orow[h * 64 + lane] = (u32)f2b(c0[h].x * iv) | ((u32)f2b(c0[h].y * iv) << 16);
      }
    }
    if (has1) {
      u32* orow = aggx + (size_t)n1 * 256;
      #pragma unroll
      for (int h = 0; h < 4; h++) {
        float iv = 1.f / (e1[h] + 1e-16f);
        orow[h * 64 + lane] = (u32)f2b(c1[h].x * iv) | ((u32)f2b(c1[h].y * iv) << 16);
      }
    }
    return;
  }
  // slow path (deg > 64): chunked, one node at a time
  for (int pass = 0; pass < 2; pass++) {
    if (pass == 1 && !has1) break;
    int n = pass ? n1 : n0;
    int beg = pass ? beg1 : beg0;
    int end = pass ? end1 : end0;
    float4 ad = pass ? adv1 : ad0;
    float e0[4] = {};
    f32x2 c0[4] = {};
    for (int base = beg; base < end; base += 64) {
      int cnt = min(64, end - base);
      int sreg = 0;
      float w0[4] = {};
      if (lane < cnt) {
        sreg = srcs[base + lane];
        float4 a = as1[sreg];
        w0[0] = __expf(lrelu(a.x + ad.x)); w0[1] = __expf(lrelu(a.y + ad.y));
        w0[2] = __expf(lrelu(a.z + ad.z)); w0[3] = __expf(lrelu(a.w + ad.w));
      }
      int cpad = (cnt + 1) & ~1;
      for (int j = 0; j < cpad; j += 2) {
        u32 dA = xb[(size_t)rdl(sreg, j) * 64 + lane];
        u32 dB = xb[(size_t)rdl(sreg, j + 1) * 64 + lane];
        f32x2 xA = bunpack(dA), xB = bunpack(dB);
        #pragma unroll
        for (int h = 0; h < 4; h++) {
          float a = rdlf(w0[h], j), b = rdlf(w0[h], j + 1);
          e0[h] += a + b;
          c0[h] += xA * a;
          c0[h] += xB * b;
        }
      }
    }
    u32* orow = aggx + (size_t)n * 256;
    #pragma unroll
    for (int h = 0; h < 4; h++) {
      float iv = 1.f / (e0[h] + 1e-16f);
      orow[h * 64 + lane] = (u32)f2b(c0[h].x * iv) | ((u32)f2b(c0[h].y * iv) << 16);
    }
  }
}

// ---------------- per-head GEMM: raw1[:, hC:(h+1)C] = aggx[:,h,:] @ W1[:,hC:(h+1)C] + b1 ----------------
__global__ __launch_bounds__(256) void k_gemm_head(
    const u16* __restrict__ A,    // aggx [M][512]
    const u16* __restrict__ Bt,   // W1t  [512][128]
    const float* __restrict__ bias,
    u16* __restrict__ C,          // raw1 [M][512]
    int M) {
  __shared__ u16 As[128 * 64];
  __shared__ u16 Bs[128 * 64];
  int t = threadIdx.x;
  int lane = t & 63, wid = t >> 6;
  int wr = wid >> 1, wc = wid & 1;
  int r0 = blockIdx.x * 128;
  int hh = blockIdx.y;
  const u16* Ah = A + hh * 128;
  const u16* Bh = Bt + (size_t)hh * 128 * 128;
  int lr = lane & 15, lk = lane >> 4;
  f32x4 acc[4][4] = {};
  for (int kt = 0; kt < 128; kt += 64) {
    #pragma unroll
    for (int it = 0; it < 4; it++) {
      int q = wid * 4096 + it * 1024 + lane * 16;
      int row = q >> 7;
      int soff = ((q >> 4) & 7) ^ (row & 7);
      {
        int gr = r0 + row; if (gr >= M) gr = M - 1;
        const u16* gp = Ah + (size_t)gr * 512 + kt + soff * 8;
        __builtin_amdgcn_global_load_lds(
            (const __attribute__((address_space(1))) void*)gp,
            (__attribute__((address_space(3))) void*)((char*)As + wid * 4096 + it * 1024),
            16, 0, 0);
      }
      {
        const u16* gp = Bh + (size_t)row * 128 + kt + soff * 8;
        __builtin_amdgcn_global_load_lds(
            (const __attribute__((address_space(1))) void*)gp,
            (__attribute__((address_space(3))) void*)((char*)Bs + wid * 4096 + it * 1024),
            16, 0, 0);
      }
    }
    __syncthreads();
    const char* Ab = (const char*)As;
    const char* Bb = (const char*)Bs;
    #pragma unroll
    for (int kk = 0; kk < 2; kk++) {
      short8 a[4], b[4];
      #pragma unroll
      for (int m = 0; m < 4; m++) {
        int row = wr * 64 + m * 16 + lr;
        int off = (row << 7) + kk * 64 + lk * 16;
        off ^= (row & 7) << 4;
        a[m] = *(const short8*)(Ab + off);
      }
      #pragma unroll
      for (int nn = 0; nn < 4; nn++) {
        int row = wc * 64 + nn * 16 + lr;
        int off = (row << 7) + kk * 64 + lk * 16;
        off ^= (row & 7) << 4;
        b[nn] = *(const short8*)(Bb + off);
      }
      #pragma unroll
      for (int m = 0; m < 4; m++)
        #pragma unroll
        for (int nn = 0; nn < 4; nn++)
          acc[m][nn] = __builtin_amdgcn_mfma_f32_16x16x32_bf16(a[m], b[nn], acc[m][nn], 0, 0, 0);
    }
    __syncthreads();
  }
  #pragma unroll
  for (int m = 0; m < 4; m++)
    #pragma unroll
    for (int nn = 0; nn < 4; nn++)
      #pragma unroll
      for (int r = 0; r < 4; r++) {
        int row = r0 + wr * 64 + m * 16 + lk * 4 + r;
        if (row < M) {
          int gcol = hh * 128 + wc * 64 + nn * 16 + lr;
          C[(size_t)row * 512 + gcol] = f2b(acc[m][nn][r] + bias[gcol]);
        }
      }
}

// ---------------- LN+ReLU over 512 channels (bf16 in/out) ----------------
__global__ __launch_bounds__(256) void k_ln512(const u16* __restrict__ raw,
                                               const float* __restrict__ gam,
                                               const float* __restrict__ bet,
                                               u16* __restrict__ out, int N) {
  int n = blockIdx.x * 4 + (threadIdx.x >> 6);
  int lane = threadIdx.x & 63;
  if (n >= N) return;
  const uint4* r = (const uint4*)(raw + (size_t)n * 512);
  uint4 q = r[lane];
  float v[8];
  v[0] = blo(q.x); v[1] = bhi(q.x); v[2] = blo(q.y); v[3] = bhi(q.y);
  v[4] = blo(q.z); v[5] = bhi(q.z); v[6] = blo(q.w); v[7] = bhi(q.w);
  float s1 = 0.f, s2 = 0.f;
  #pragma unroll
  for (int j = 0; j < 8; j++) { s1 += v[j]; s2 += v[j] * v[j]; }
  #pragma unroll
  for (int off = 32; off; off >>= 1) {
    s1 += __shfl_xor(s1, off);
    s2 += __shfl_xor(s2, off);
  }
  float mean = s1 * (1.f / 512.f);
  float var = s2 * (1.f / 512.f) - mean * mean;
  float rs = rsqrtf(var + 1e-5f);
  u32 o[4];
  #pragma unroll
  for (int j = 0; j < 4; j++) {
    int ch = lane * 8 + 2 * j;
    float y0 = fmaxf((v[2 * j] - mean) * rs * gam[ch] + bet[ch], 0.f);
    float y1 = fmaxf((v[2 * j + 1] - mean) * rs * gam[ch + 1] + bet[ch + 1], 0.f);
    o[j] = (u32)f2b(y0) | ((u32)f2b(y1) << 16);
  }
  ((uint4*)(out + (size_t)n * 512))[lane] = make_uint4(o[0], o[1], o[2], o[3]);
}

// ---------------- bf16 MFMA GEMM (conv2): C[M][128] = A[M][512] * Bt[128][512]^T ----------------
__global__ __launch_bounds__(256) void k_gemm_bf16(
    const u16* __restrict__ A, const u16* __restrict__ Bt,
    u16* __restrict__ C, int M, int Nc, int K) {
  __shared__ u16 As[128 * 64];
  __shared__ u16 Bs[128 * 64];
  int t = threadIdx.x;
  int lane = t & 63, wid = t >> 6;
  int wr = wid >> 1, wc = wid & 1;
  int r0 = blockIdx.x * 128, c0 = blockIdx.y * 128;
  int lr = lane & 15, lk = lane >> 4;
  f32x4 acc[4][4] = {};
  for (int kt = 0; kt < K; kt += 64) {
    #pragma unroll
    for (int it = 0; it < 4; it++) {
      int q = wid * 4096 + it * 1024 + lane * 16;
      int row = q >> 7;
      int soff = ((q >> 4) & 7) ^ (row & 7);
      {
        int gr = r0 + row; if (gr >= M) gr = M - 1;
        const u16* gp = A + (size_t)gr * K + kt + soff * 8;
        __builtin_amdgcn_global_load_lds(
            (const __attribute__((address_space(1))) void*)gp,
            (__attribute__((address_space(3))) void*)((char*)As + wid * 4096 + it * 1024),
            16, 0, 0);
      }
      {
        int gn = c0 + row;
        const u16* gp = Bt + (size_t)gn * K + kt + soff * 8;
        __builtin_amdgcn_global_load_lds(
            (const __attribute__((address_space(1))) void*)gp,
            (__attribute__((address_space(3))) void*)((char*)Bs + wid * 4096 + it * 1024),
            16, 0, 0);
      }
    }
    __syncthreads();
    const char* Ab = (const char*)As;
    const char* Bb = (const char*)Bs;
    #pragma unroll
    for (int kk = 0; kk < 2; kk++) {
      short8 a[4], b[4];
      #pragma unroll
      for (int m = 0; m < 4; m++) {
        int row = wr * 64 + m * 16 + lr;
        int off = (row << 7) + kk * 64 + lk * 16;
        off ^= (row & 7) << 4;
        a[m] = *(const short8*)(Ab + off);
      }
      #pragma unroll
      for (int nn = 0; nn < 4; nn++) {
        int row = wc * 64 + nn * 16 + lr;
        int off = (row << 7) + kk * 64 + lk * 16;
        off ^= (row & 7) << 4;
        b[nn] = *(const short8*)(Bb + off);
      }
      #pragma unroll
      for (int m = 0; m < 4; m++)
        #pragma unroll
        for (int nn = 0; nn < 4; nn++)
          acc[m][nn] = __builtin_amdgcn_mfma_f32_16x16x32_bf16(a[m], b[nn], acc[m][nn], 0, 0, 0);
    }
    __syncthreads();
  }
  #pragma unroll
  for (int m = 0; m < 4; m++)
    #pragma unroll
    for (int nn = 0; nn < 4; nn++)
      #pragma unroll
      for (int r = 0; r < 4; r++) {
        int row = r0 + wr * 64 + m * 16 + lk * 4 + r;
        if (row < M) {
          int col = c0 + wc * 64 + nn * 16 + lr;
          C[(size_t)row * Nc + col] = f2b(acc[m][nn][r]);
        }
      }
}

// ---------------- conv2 scores ----------------
__global__ void k_att_h1(const u16* __restrict__ hm, const float* __restrict__ att_s,
                         const float* __restrict__ att_d, float* __restrict__ s_out,
                         float* __restrict__ d_out, int N) {
  int n = blockIdx.x * (blockDim.x >> 6) + (threadIdx.x >> 6);
  int lane = threadIdx.x & 63;
  if (n >= N) return;
  const u32* row = (const u32*)(hm + (size_t)n * CH);
  u32 d = row[lane];
  float x0 = blo(d), x1 = bhi(d);
  float ps = x0 * att_s[2 * lane] + x1 * att_s[2 * lane + 1];
  float pd = x0 * att_d[2 * lane] + x1 * att_d[2 * lane + 1];
  #pragma unroll
  for (int off = 32; off; off >>= 1) {
    ps += __shfl_xor(ps, off);
    pd += __shfl_xor(pd, off);
  }
  if (lane == 0) { s_out[n] = ps; d_out[n] = pd; }
}

// ---------------- conv2 aggregation + bias + LN + ReLU -> h2 (fp32), no atomics ----------------
// Two nodes per wave; readlane broadcasts; pk_fma; tail-split.
__global__ __launch_bounds__(256) void k_agg2f(
    const u32* __restrict__ raw2, const int* __restrict__ indptr,
    const int* __restrict__ srcs, const float* __restrict__ as2,
    const float* __restrict__ ad2, const float* __restrict__ bias,
    const float* __restrict__ gam, const float* __restrict__ bet,
    float* __restrict__ h2, int N) {
  int t = threadIdx.x;
  int lane = t & 63, wid = t >> 6;
  int n0 = blockIdx.x * 8 + wid * 2;
  if (n0 >= N) return;
  int n1 = n0 + 1;
  bool has1 = n1 < N;
  int beg0 = indptr[n0], end0 = indptr[n0 + 1];
  int beg1 = end0, end1 = has1 ? indptr[n1 + 1] : end0;
  int deg0 = end0 - beg0, deg1 = end1 - beg1;
  float adv0 = ad2[n0];
  float adv1 = has1 ? ad2[n1] : 0.f;
  float ds0 = 0.f, ds1 = 0.f;
  f32x2 acc0 = {0.f, 0.f}, acc1 = {0.f, 0.f};

  if (deg0 <= 64 && deg1 <= 64) {
    int s0 = 0, s1r = 0;
    float w0 = 0.f, w1 = 0.f;
    if (lane < deg0) { s0 = srcs[beg0 + lane]; w0 = __expf(lrelu(as2[s0] + adv0)); }
    if (lane < deg1) { s1r = srcs[beg1 + lane]; w1 = __expf(lrelu(as2[s1r] + adv1)); }
    int dboth = (deg0 < deg1 ? deg0 : deg1) & ~7;
    int j = 0;
    for (; j < dboth; j += 8) {
      u32 d[8], e[8];
      #pragma unroll
      for (int u = 0; u < 8; u++) d[u] = raw2[(size_t)rdl(s0, j + u) * 64 + lane];
      #pragma unroll
      for (int u = 0; u < 8; u++) e[u] = raw2[(size_t)rdl(s1r, j + u) * 64 + lane];
      #pragma unroll
      for (int u = 0; u < 8; u++) {
        acc0 += bunpack(d[u]) * rdlf(w0, j + u);
        acc1 += bunpack(e[u]) * rdlf(w1, j + u);
      }
    }
    int pad0 = (deg0 + 3) & ~3;
    for (int ja = j; ja < pad0; ja += 4) {
      u32 d[4];
      #pragma unroll
      for (int u = 0; u < 4; u++) d[u] = raw2[(size_t)rdl(s0, ja + u) * 64 + lane];
      #pragma unroll
      for (int u = 0; u < 4; u++) acc0 += bunpack(d[u]) * rdlf(w0, ja + u);
    }
    int pad1 = (deg1 + 3) & ~3;
    for (int jb = j; jb < pad1; jb += 4) {
      u32 e[4];
      #pragma unroll
      for (int u = 0; u < 4; u++) e[u] = raw2[(size_t)rdl(s1r, jb + u) * 64 + lane];
      #pragma unroll
      for (int u = 0; u < 4; u++) acc1 += bunpack(e[u]) * rdlf(w1, jb + u);
    }
    // denominators via butterflies
    float v0 = w0, v1 = w1;
    #pragma unroll
    for (int off = 32; off; off >>= 1) {
      v0 += __shfl_xor(v0, off);
      v1 += __shfl_xor(v1, off);
    }
    ds0 = v0; ds1 = v1;
  } else {
    // slow path: chunked, node0 then node1
    for (int pass = 0; pass < 2; pass++) {
      if (pass == 1 && !has1) break;
      int beg = pass ? beg1 : beg0;
      int end = pass ? end1 : end0;
      float adv = pass ? adv1 : adv0;
      for (int base = beg; base < end; base += 64) {
        int cnt = min(64, end - base);
        int sreg = 0;
        float w = 0.f;
        if (lane < cnt) { sreg = srcs[base + lane]; w = __expf(lrelu(as2[sreg] + adv)); }
        int cpad = (cnt + 3) & ~3;
        for (int j = 0; j < cpad; j += 4) {
          u32 dA = raw2[(size_t)rdl(sreg, j) * 64 + lane];
          u32 dB = raw2[(size_t)rdl(sreg, j + 1) * 64 + lane];
          u32 dC = raw2[(size_t)rdl(sreg, j + 2) * 64 + lane];
          u32 dD = raw2[(size_t)rdl(sreg, j + 3) * 64 + lane];
          float wA = rdlf(w, j), wB = rdlf(w, j + 1);
          float wC = rdlf(w, j + 2), wD = rdlf(w, j + 3);
          f32x2 s = bunpack(dA) * wA;
          s += bunpack(dB) * wB;
          s += bunpack(dC) * wC;
          s += bunpack(dD) * wD;
          float sw = (wA + wB) + (wC + wD);
          if (pass) { ds1 += sw; acc1 += s; }
          else      { ds0 += sw; acc0 += s; }
        }
      }
    }
  }

  // LN + ReLU, both nodes (butterflies interleaved), write h2 rows
  float inv0 = 1.f / (ds0 + 1e-16f);
  float v00 = acc0.x * inv0 + bias[2 * lane];
  float v01 = acc0.y * inv0 + bias[2 * lane + 1];
  float s1a = v00 + v01, s2a = v00 * v00 + v01 * v01;
  float inv1 = 1.f / (ds1 + 1e-16f);
  float v10 = acc1.x * inv1 + bias[2 * lane];
  float v11 = acc1.y * inv1 + bias[2 * lane + 1];
  float s1b = v10 + v11, s2b = v10 * v10 + v11 * v11;
  #pragma unroll
  for (int off = 32; off; off >>= 1) {
    s1a += __shfl_xor(s1a, off);
    s2a += __shfl_xor(s2a, off);
    s1b += __shfl_xor(s1b, off);
    s2b += __shfl_xor(s2b, off);
  }
  {
    float mean = s1a * (1.f / 128.f);
    float var = s2a * (1.f / 128.f) - mean * mean;
    float rs = rsqrtf(var + 1e-5f);
    float y0 = fmaxf((v00 - mean) * rs * gam[2 * lane] + bet[2 * lane], 0.f);
    float y1 = fmaxf((v01 - mean) * rs * gam[2 * lane + 1] + bet[2 * lane + 1], 0.f);
    ((float2*)(h2 + (size_t)n0 * 128))[lane] = make_float2(y0, y1);
  }
  if (has1) {
    float mean = s1b * (1.f / 128.f);
    float var = s2b * (1.f / 128.f) - mean * mean;
    float rs = rsqrtf(var + 1e-5f);
    float y0 = fmaxf((v10 - mean) * rs * gam[2 * lane] + bet[2 * lane], 0.f);
    float y1 = fmaxf((v11 - mean) * rs * gam[2 * lane + 1] + bet[2 * lane + 1], 0.f);
    ((float2*)(h2 + (size_t)n1 * 128))[lane] = make_float2(y0, y1);
  }
}

// ---------------- MLP head with segment-sum pooling (batch is sorted; no atomics) ----------------
__global__ __launch_bounds__(256) void k_head(const float* __restrict__ h2,
    const int* __restrict__ batch, int N,
    const float* __restrict__ rW1, const float* __restrict__ rb1,
    const float* __restrict__ rg, const float* __restrict__ rbe,
    const float* __restrict__ rW2, const float* __restrict__ rb2,
    float* __restrict__ outp) {
  int g = blockIdx.x, t = threadIdx.x;
  int ch = t & 127, half = t >> 7;
  __shared__ float part[2][128];
  __shared__ float pl[128];
  __shared__ float yv[32];
  __shared__ float rv[32];
  __shared__ float mv[2];
  __shared__ int sseg[2];
  if (t == 0) {
    int lo = 0, hi = N;
    while (lo < hi) { int mid = (lo + hi) >> 1; if (batch[mid] < g) lo = mid + 1; else hi = mid; }
    int lo2 = lo, hi2 = N;
    while (lo2 < hi2) { int mid = (lo2 + hi2) >> 1; if (batch[mid] < g + 1) lo2 = mid + 1; else hi2 = mid; }
    sseg[0] = lo; sseg[1] = lo2;
  }
  __syncthreads();
  int lo = sseg[0], hi = sseg[1];
  float s = 0.f;
  int n = lo + half;
  for (; n + 8 <= hi; n += 8) {
    s += h2[(size_t)n * 128 + ch] + h2[(size_t)(n + 2) * 128 + ch]
       + h2[(size_t)(n + 4) * 128 + ch] + h2[(size_t)(n + 6) * 128 + ch];
  }
  for (; n < hi; n += 2) s += h2[(size_t)n * 128 + ch];
  part[half][ch] = s;
  __syncthreads();
  float cnt = fmaxf((float)(hi - lo), 1.f);
  if (t < 128) pl[t] = (part[0][t] + part[1][t]) / cnt;
  __syncthreads();
  if (t < 32) {
    float sum = rb1[t];
    for (int c = 0; c < 128; c++) sum += pl[c] * rW1[c * 32 + t];
    yv[t] = sum;
  }
  __syncthreads();
  if (t == 0) {
    float sm = 0.f, sq = 0.f;
    for (int j = 0; j < 32; j++) { sm += yv[j]; sq += yv[j] * yv[j]; }
    float mean = sm / 32.f;
    float var = sq / 32.f - mean * mean;
    mv[0] = mean; mv[1] = rsqrtf(var + 1e-5f);
  }
  __syncthreads();
  if (t < 32) {
    float y = (yv[t] - mv[0]) * mv[1] * rg[t] + rbe[t];
    rv[t] = fmaxf(y, 0.f);
  }
  __syncthreads();
  if (t < OUT_DIM) {
    float sum = rb2[t];
    for (int j = 0; j < 32; j++) sum += rv[j] * rW2[j * 8 + t];
    outp[g * 8 + t] = sum;
  }
}

extern "C" void kernel_launch(void* const* d_in, const int* in_sizes, int n_in,
                              void* d_out, int out_size, void* d_ws, size_t ws_size,
                              hipStream_t stream) {
  const float* x    = (const float*)d_in[0];
  const int*   ei   = (const int*)d_in[1];
  const int*   batch= (const int*)d_in[3];
  const float* W1   = (const float*)d_in[4];
  const float* as1w = (const float*)d_in[5];
  const float* ad1w = (const float*)d_in[6];
  const float* b1   = (const float*)d_in[7];
  const float* g1   = (const float*)d_in[8];
  const float* be1  = (const float*)d_in[9];
  const float* W2   = (const float*)d_in[10];
  const float* as2w = (const float*)d_in[11];
  const float* ad2w = (const float*)d_in[12];
  const float* b2   = (const float*)d_in[13];
  const float* g2   = (const float*)d_in[14];
  const float* be2  = (const float*)d_in[15];
  const float* rW1  = (const float*)d_in[16];
  const float* rb1  = (const float*)d_in[17];
  const float* rg   = (const float*)d_in[18];
  const float* rbe  = (const float*)d_in[19];
  const float* rW2  = (const float*)d_in[20];
  const float* rb2  = (const float*)d_in[21];

  int N = in_sizes[0] / 128;
  int E = in_sizes[1] / 2;
  int ET = E + N;
  int nb = (N + 255) / 256;

  char* p = (char*)d_ws;
  u16* x_b   = (u16*)p; p += (size_t)N * 128 * 2;
  u16* aggx  = (u16*)p; p += (size_t)N * 512 * 2;
  u16* raw1  = (u16*)p; p += (size_t)N * 512 * 2;
  u16* h1_b  = (u16*)p; p += (size_t)N * 512 * 2;
  u16* raw2b = (u16*)p; p += (size_t)N * 128 * 2;
  float* h2  = (float*)p; p += (size_t)N * 128 * 4;
  u16* W1t   = (u16*)p; p += 512 * 128 * 2;
  u16* W2t   = (u16*)p; p += 128 * 512 * 2;
  float* ws  = (float*)p; p += 128 * 8 * 4;
  float* sa1 = (float*)p; p += (size_t)N * 4 * 4;
  float* da1 = (float*)p; p += (size_t)N * 4 * 4;
  float* sa2 = (float*)p; p += (size_t)N * 4;
  float* da2 = (float*)p; p += (size_t)N * 4;
  int* counts = (int*)p; p += (size_t)N * 4;
  int* indptr = (int*)p; p += (size_t)(N + 1) * 4;
  int* cursor = (int*)p; p += (size_t)N * 4;
  int* bsum   = (int*)p; p += (size_t)nb * 4;
  int* boff   = (int*)p; p += (size_t)nb * 4;
  int* srcs   = (int*)p; p += (size_t)ET * 4;

  hipMemsetAsync(counts, 0, (size_t)N * sizeof(int), stream);

  int eb = (ET + 255) / 256;

  // weight prep (one kernel)
  k_wprep<<<516, 256, 0, stream>>>(W1, W2, as1w, ad1w, W1t, W2t, ws);

  // edge counting + x conversion + conv1 scores (one kernel)
  int pb = (N + 3) / 4;
  k_count_prep<<<eb + pb, 256, 0, stream>>>(ei, counts, E, N, eb, x, ws,
                                            (u32*)x_b, (float4*)sa1, (float4*)da1);

  k_scanA<<<nb, 256, 0, stream>>>(counts, bsum, N);
  k_scanB<<<1, 1024, 0, stream>>>(bsum, boff, nb);
  k_scanC<<<nb, 256, 0, stream>>>(counts, boff, indptr, cursor, N);
  k_scatter<<<eb, 256, 0, stream>>>(ei, cursor, srcs, E, N);

  // conv1: aggregate x (2 nodes per wave), per-head GEMM (+bias), LN+ReLU
  k_aggx<<<(N + 7) / 8, 256, 0, stream>>>((const u32*)x_b, indptr, srcs,
                                          (const float4*)sa1, (const float4*)da1,
                                          (u32*)aggx, N);
  dim3 gridh((N + 127) / 128, 4);
  k_gemm_head<<<gridh, 256, 0, stream>>>(aggx, W1t, b1, raw1, N);
  k_ln512<<<(N + 3) / 4, 256, 0, stream>>>(raw1, g1, be1, h1_b, N);

  // conv2
  dim3 grid2((N + 127) / 128, 1);
  k_gemm_bf16<<<grid2, 256, 0, stream>>>(h1_b, W2t, raw2b, N, 128, 512);
  k_att_h1<<<(N + 3) / 4, 256, 0, stream>>>(raw2b, as2w, ad2w, sa2, da2, N);
  k_agg2f<<<(N + 7) / 8, 256, 0, stream>>>((const u32*)raw2b, indptr, srcs, sa2, da2,
                                           b2, g2, be2, h2, N);

  // head: segment-sum pooling (batch sorted) + MLP
  k_head<<<GRAPHS, 256, 0, stream>>>(h2, batch, N, rW1, rb1, rg, rbe, rW2, rb2,
                                     (float*)d_out);
}

// Round 11
// 319.228 us; speedup vs baseline: 1.5523x; 1.0170x over previous
//
#include <hip/hip_runtime.h>
#include <math.h>

#define HEADS 4
#define CH 128
#define HC 512
#define GRAPHS 128
#define OUT_DIM 8

typedef unsigned short u16;
typedef unsigned int u32;
typedef short short8 __attribute__((ext_vector_type(8)));
typedef float f32x4 __attribute__((ext_vector_type(4)));
typedef float f32x2 __attribute__((ext_vector_type(2)));

__device__ inline u16 f2b(float f) {
  u32 u = __float_as_uint(f);
  u32 r = u + 0x7FFFu + ((u >> 16) & 1u);
  return (u16)(r >> 16);
}
__device__ inline float blo(u32 d) { return __uint_as_float(d << 16); }
__device__ inline float bhi(u32 d) { return __uint_as_float(d & 0xffff0000u); }
__device__ inline f32x2 bunpack(u32 d) {
  f32x2 r; r.x = blo(d); r.y = bhi(d); return r;
}
__device__ inline float lrelu(float v) { return v > 0.f ? v : 0.2f * v; }
// wave-uniform broadcast via v_readlane (SGPR result) — never ds_bpermute
__device__ inline int rdl(int v, int l) { return __builtin_amdgcn_readlane(v, l); }
__device__ inline float rdlf(float v, int l) {
  return __int_as_float(__builtin_amdgcn_readlane(__float_as_int(v), l));
}

// ---------------- CSR build ----------------
__global__ __launch_bounds__(256) void k_scanA(const int* __restrict__ counts,
                                               int* __restrict__ bsum, int N) {
  __shared__ int sh[256];
  int b = blockIdx.x, t = threadIdx.x, i = b * 256 + t;
  sh[t] = (i < N) ? counts[i] : 0;
  __syncthreads();
  for (int off = 128; off; off >>= 1) {
    if (t < off) sh[t] += sh[t + off];
    __syncthreads();
  }
  if (t == 0) bsum[b] = sh[0];
}

__global__ __launch_bounds__(1024) void k_scanB(const int* __restrict__ bsum,
                                                int* __restrict__ boff, int nb) {
  __shared__ int sh[1024];
  int t = threadIdx.x;
  sh[t] = (t < nb) ? bsum[t] : 0;
  __syncthreads();
  for (int off = 1; off < 1024; off <<= 1) {
    int v = sh[t];
    int u = (t >= off) ? sh[t - off] : 0;
    __syncthreads();
    sh[t] = v + u;
    __syncthreads();
  }
  if (t < nb) boff[t] = (t == 0) ? 0 : sh[t - 1];
}

__global__ __launch_bounds__(256) void k_scanC(const int* __restrict__ counts,
                                               const int* __restrict__ boff,
                                               int* __restrict__ indptr,
                                               int* __restrict__ cursor, int N) {
  __shared__ int sh[256];
  int b = blockIdx.x, t = threadIdx.x, i = b * 256 + t;
  int v = (i < N) ? counts[i] : 0;
  sh[t] = v;
  __syncthreads();
  for (int off = 1; off < 256; off <<= 1) {
    int a = sh[t];
    int u = (t >= off) ? sh[t - off] : 0;
    __syncthreads();
    sh[t] = a + u;
    __syncthreads();
  }
  if (i < N) {
    int excl = boff[b] + sh[t] - v;
    indptr[i] = excl;
    cursor[i] = excl;
    if (i == N - 1) indptr[N] = excl + v;
  }
}

__global__ void k_scatter(const int* __restrict__ ei, int* __restrict__ cursor,
                          int* __restrict__ srcs, int E, int N) {
  int i = blockIdx.x * blockDim.x + threadIdx.x;
  int total = E + N;
  if (i >= total) return;
  int src, dst;
  if (i < E) { src = ei[i]; dst = ei[E + i]; } else { src = i - E; dst = i - E; }
  int pos = atomicAdd(&cursor[dst], 1);
  srcs[pos] = src;
}

// ---------------- merged weight prep: W1t, W2t, wst ----------------
// blocks [0,256): W1t;  [256,512): W2t;   516: wst (score matrix, bf16 [16][128])
__global__ __launch_bounds__(256) void k_wprep(const float* __restrict__ W1,
                                               const float* __restrict__ W2,
                                               const float* __restrict__ as1,
                                               const float* __restrict__ ad1,
                                               u16* __restrict__ W1t,
                                               u16* __restrict__ W2t,
                                               u16* __restrict__ wst) {
  int b = blockIdx.x, t = threadIdx.x;
  if (b < 256) {
    int i = b * 256 + t;               // Wt index over [512][128]
    int n = i >> 7, k = i & 127;
    W1t[i] = f2b(W1[(size_t)k * HC + n]);
  } else if (b < 512) {
    int i = (b - 256) * 256 + t;       // Wt index over [128][512]
    int n = i >> 9, k = i & 511;
    W2t[i] = f2b(W2[(size_t)k * CH + n]);
  } else {
    // wst[o][k] = sum_c W1[k][h*CH+c] * att[h][c]; o in 0..3 src heads, 4..7 dst heads
    for (int idx = t; idx < 16 * 128; idx += 256) {
      int o = idx >> 7, k = idx & 127;
      float s = 0.f;
      if (o < 8) {
        int h = o & 3;
        const float* av = ((o < 4) ? as1 : ad1) + h * CH;
        const float* wrow = W1 + (size_t)k * HC + h * CH;
        for (int c = 0; c < CH; c++) s += wrow[c] * av[c];
      }
      wst[idx] = f2b(s);
    }
  }
}

// ---------------- merged: edge-count atomics + x->bf16 (flat streaming) ----------------
__global__ void k_count_prep(const int* __restrict__ ei, int* __restrict__ counts,
                             int E, int N, int eb,
                             const float* __restrict__ x, uint2* __restrict__ xb2) {
  if ((int)blockIdx.x < eb) {
    int i = blockIdx.x * 256 + threadIdx.x;
    int total = E + N;
    if (i >= total) return;
    int dst = (i < E) ? ei[E + i] : (i - E);
    atomicAdd(&counts[dst], 1);
    return;
  }
  int i = (blockIdx.x - eb) * 256 + threadIdx.x;   // over N*32 float4s
  if (i >= N * 32) return;
  float4 v = ((const float4*)x)[i];
  uint2 o;
  o.x = (u32)f2b(v.x) | ((u32)f2b(v.y) << 16);
  o.y = (u32)f2b(v.z) | ((u32)f2b(v.w) << 16);
  xb2[i] = o;
}

// ---------------- conv1 scores via MFMA: scores[N,8] = xb @ wst^T ----------------
// 4 waves/block, 64 rows/wave. C layout: col=lane&15, row=(lane>>4)*4+r (m89).
__global__ __launch_bounds__(256) void k_score(
    const u16* __restrict__ xb, const u16* __restrict__ wst,
    float* __restrict__ sa1, float* __restrict__ da1, int N) {
  int lane = threadIdx.x & 63, wid = threadIdx.x >> 6;
  int base = (blockIdx.x * 4 + wid) * 64;
  if (base >= N) return;
  int lr = lane & 15, lk = lane >> 4;
  short8 bfrag[4];
  #pragma unroll
  for (int ks = 0; ks < 4; ks++)
    bfrag[ks] = *(const short8*)(wst + lr * 128 + ks * 32 + lk * 8);
  #pragma unroll
  for (int rt = 0; rt < 4; rt++) {
    int r0 = base + rt * 16;
    if (r0 >= N) break;
    f32x4 acc = {};
    int row = r0 + lr; if (row >= N) row = N - 1;
    #pragma unroll
    for (int ks = 0; ks < 4; ks++) {
      short8 afrag = *(const short8*)(xb + (size_t)row * 128 + ks * 32 + lk * 8);
      acc = __builtin_amdgcn_mfma_f32_16x16x32_bf16(afrag, bfrag[ks], acc, 0, 0, 0);
    }
    int col = lr;
    #pragma unroll
    for (int r = 0; r < 4; r++) {
      int n = r0 + lk * 4 + r;
      if (n < N) {
        if (col < 4) sa1[n * 4 + col] = acc[r];
        else if (col < 8) da1[n * 4 + (col - 4)] = acc[r];
      }
    }
  }
}

// ---------------- conv1 aggregation over x (bf16), 4 heads ----------------
// Two nodes per wave; readlane broadcasts; pk_fma accumulators; tail-split.
__global__ __launch_bounds__(256) void k_aggx(
    const u32* __restrict__ xb, const int* __restrict__ indptr,
    const int* __restrict__ srcs, const float4* __restrict__ as1,
    const float4* __restrict__ ad1, u32* __restrict__ aggx, int N) {
  int t = threadIdx.x;
  int lane = t & 63, wid = t >> 6;
  int n0 = blockIdx.x * 8 + wid * 2;
  if (n0 >= N) return;
  int n1 = n0 + 1;
  bool has1 = n1 < N;
  int beg0 = indptr[n0], end0 = indptr[n0 + 1];
  int beg1 = end0, end1 = has1 ? indptr[n1 + 1] : end0;
  int deg0 = end0 - beg0, deg1 = end1 - beg1;
  float4 ad0 = ad1[n0];
  float4 adv1 = has1 ? ad1[n1] : make_float4(0.f, 0.f, 0.f, 0.f);

  if (deg0 <= 64 && deg1 <= 64) {
    int s0 = 0, s1 = 0;
    float w0[4] = {}, w1[4] = {};
    if (lane < deg0) {
      s0 = srcs[beg0 + lane];
      float4 a = as1[s0];
      w0[0] = __expf(lrelu(a.x + ad0.x)); w0[1] = __expf(lrelu(a.y + ad0.y));
      w0[2] = __expf(lrelu(a.z + ad0.z)); w0[3] = __expf(lrelu(a.w + ad0.w));
    }
    if (lane < deg1) {
      s1 = srcs[beg1 + lane];
      float4 a = as1[s1];
      w1[0] = __expf(lrelu(a.x + adv1.x)); w1[1] = __expf(lrelu(a.y + adv1.y));
      w1[2] = __expf(lrelu(a.z + adv1.z)); w1[3] = __expf(lrelu(a.w + adv1.w));
    }
    f32x2 c0[4] = {}, c1[4] = {};
    int dboth = (deg0 < deg1 ? deg0 : deg1) & ~3;
    int j = 0;
    for (; j < dboth; j += 4) {
      u32 d[4], e[4];
      #pragma unroll
      for (int u = 0; u < 4; u++) d[u] = xb[(size_t)rdl(s0, j + u) * 64 + lane];
      #pragma unroll
      for (int u = 0; u < 4; u++) e[u] = xb[(size_t)rdl(s1, j + u) * 64 + lane];
      #pragma unroll
      for (int u = 0; u < 4; u++) {
        f32x2 xv = bunpack(d[u]);
        f32x2 yv = bunpack(e[u]);
        #pragma unroll
        for (int h = 0; h < 4; h++) {
          c0[h] += xv * rdlf(w0[h], j + u);
          c1[h] += yv * rdlf(w1[h], j + u);
        }
      }
    }
    int pad0 = (deg0 + 3) & ~3;
    for (int ja = j; ja < pad0; ja += 4) {
      u32 d[4];
      #pragma unroll
      for (int u = 0; u < 4; u++) d[u] = xb[(size_t)rdl(s0, ja + u) * 64 + lane];
      #pragma unroll
      for (int u = 0; u < 4; u++) {
        f32x2 xv = bunpack(d[u]);
        #pragma unroll
        for (int h = 0; h < 4; h++) c0[h] += xv * rdlf(w0[h], ja + u);
      }
    }
    int pad1 = (deg1 + 3) & ~3;
    for (int jb = j; jb < pad1; jb += 4) {
      u32 e[4];
      #pragma unroll
      for (int u = 0; u < 4; u++) e[u] = xb[(size_t)rdl(s1, jb + u) * 64 + lane];
      #pragma unroll
      for (int u = 0; u < 4; u++) {
        f32x2 yv = bunpack(e[u]);
        #pragma unroll
        for (int h = 0; h < 4; h++) c1[h] += yv * rdlf(w1[h], jb + u);
      }
    }
    // denominators via butterflies (DS pipe, off the VALU critical path)
    float e0[4], e1[4];
    #pragma unroll
    for (int h = 0; h < 4; h++) {
      float v0 = w0[h], v1 = w1[h];
      #pragma unroll
      for (int off = 32; off; off >>= 1) {
        v0 += __shfl_xor(v0, off);
        v1 += __shfl_xor(v1, off);
      }
      e0[h] = v0; e1[h] = v1;
    }
    {
      u32* orow = aggx + (size_t)n0 * 256;
      #pragma unroll
      for (int h = 0; h < 4; h++) {
        float iv = 1.f / (e0[h] + 1e-16f);
        orow[h * 64 + lane] = (u32)f2b(c0[h].x * iv) | ((u32)f2b(c0[h].y * iv) << 16);
      }
    }
    if (has1) {
      u32* orow = aggx + (size_t)n1 * 256;
      #pragma unroll
      for (int h = 0; h < 4; h++) {
        float iv = 1.f / (e1[h] + 1e-16f);
        orow[h * 64 + lane] = (u32)f2b(c1[h].x * iv) | ((u32)f2b(c1[h].y * iv) << 16);
      }
    }
    return;
  }
  // slow path (deg > 64): chunked, one node at a time
  for (int pass = 0; pass < 2; pass++) {
    if (pass == 1 && !has1) break;
    int n = pass ? n1 : n0;
    int beg = pass ? beg1 : beg0;
    int end = pass ? end1 : end0;
    float4 ad = pass ? adv1 : ad0;
    float e0[4] = {};
    f32x2 c0[4] = {};
    for (int base = beg; base < end; base += 64) {
      int cnt = min(64, end - base);
      int sreg = 0;
      float w0[4] = {};
      if (lane < cnt) {
        sreg = srcs[base + lane];
        float4 a = as1[sreg];
        w0[0] = __expf(lrelu(a.x + ad.x)); w0[1] = __expf(lrelu(a.y + ad.y));
        w0[2] = __expf(lrelu(a.z + ad.z)); w0[3] = __expf(lrelu(a.w + ad.w));
      }
      int cpad = (cnt + 1) & ~1;
      for (int j = 0; j < cpad; j += 2) {
        u32 dA = xb[(size_t)rdl(sreg, j) * 64 + lane];
        u32 dB = xb[(size_t)rdl(sreg, j + 1) * 64 + lane];
        f32x2 xA = bunpack(dA), xB = bunpack(dB);
        #pragma unroll
        for (int h = 0; h < 4; h++) {
          float a = rdlf(w0[h], j), b = rdlf(w0[h], j + 1);
          e0[h] += a + b;
          c0[h] += xA * a;
          c0[h] += xB * b;
        }
      }
    }
    u32* orow = aggx + (size_t)n * 256;
    #pragma unroll
    for (int h = 0; h < 4; h++) {
      float iv = 1.f / (e0[h] + 1e-16f);
      orow[h * 64 + lane] = (u32)f2b(c0[h].x * iv) | ((u32)f2b(c0[h].y * iv) << 16);
    }
  }
}

// ---------------- per-head GEMM: raw1[:, hC:(h+1)C] = aggx[:,h,:] @ W1[:,hC:(h+1)C] + b1 ----------------
__global__ __launch_bounds__(256) void k_gemm_head(
    const u16* __restrict__ A,    // aggx [M][512]
    const u16* __restrict__ Bt,   // W1t  [512][128]
    const float* __restrict__ bias,
    u16* __restrict__ C,          // raw1 [M][512]
    int M) {
  __shared__ u16 As[128 * 64];
  __shared__ u16 Bs[128 * 64];
  int t = threadIdx.x;
  int lane = t & 63, wid = t >> 6;
  int wr = wid >> 1, wc = wid & 1;
  int r0 = blockIdx.x * 128;
  int hh = blockIdx.y;
  const u16* Ah = A + hh * 128;
  const u16* Bh = Bt + (size_t)hh * 128 * 128;
  int lr = lane & 15, lk = lane >> 4;
  f32x4 acc[4][4] = {};
  for (int kt = 0; kt < 128; kt += 64) {
    #pragma unroll
    for (int it = 0; it < 4; it++) {
      int q = wid * 4096 + it * 1024 + lane * 16;
      int row = q >> 7;
      int soff = ((q >> 4) & 7) ^ (row & 7);
      {
        int gr = r0 + row; if (gr >= M) gr = M - 1;
        const u16* gp = Ah + (size_t)gr * 512 + kt + soff * 8;
        __builtin_amdgcn_global_load_lds(
            (const __attribute__((address_space(1))) void*)gp,
            (__attribute__((address_space(3))) void*)((char*)As + wid * 4096 + it * 1024),
            16, 0, 0);
      }
      {
        const u16* gp = Bh + (size_t)row * 128 + kt + soff * 8;
        __builtin_amdgcn_global_load_lds(
            (const __attribute__((address_space(1))) void*)gp,
            (__attribute__((address_space(3))) void*)((char*)Bs + wid * 4096 + it * 1024),
            16, 0, 0);
      }
    }
    __syncthreads();
    const char* Ab = (const char*)As;
    const char* Bb = (const char*)Bs;
    #pragma unroll
    for (int kk = 0; kk < 2; kk++) {
      short8 a[4], b[4];
      #pragma unroll
      for (int m = 0; m < 4; m++) {
        int row = wr * 64 + m * 16 + lr;
        int off = (row << 7) + kk * 64 + lk * 16;
        off ^= (row & 7) << 4;
        a[m] = *(const short8*)(Ab + off);
      }
      #pragma unroll
      for (int nn = 0; nn < 4; nn++) {
        int row = wc * 64 + nn * 16 + lr;
        int off = (row << 7) + kk * 64 + lk * 16;
        off ^= (row & 7) << 4;
        b[nn] = *(const short8*)(Bb + off);
      }
      #pragma unroll
      for (int m = 0; m < 4; m++)
        #pragma unroll
        for (int nn = 0; nn < 4; nn++)
          acc[m][nn] = __builtin_amdgcn_mfma_f32_16x16x32_bf16(a[m], b[nn], acc[m][nn], 0, 0, 0);
    }
    __syncthreads();
  }
  #pragma unroll
  for (int m = 0; m < 4; m++)
    #pragma unroll
    for (int nn = 0; nn < 4; nn++)
      #pragma unroll
      for (int r = 0; r < 4; r++) {
        int row = r0 + wr * 64 + m * 16 + lk * 4 + r;
        if (row < M) {
          int gcol = hh * 128 + wc * 64 + nn * 16 + lr;
          C[(size_t)row * 512 + gcol] = f2b(acc[m][nn][r] + bias[gcol]);
        }
      }
}

// ---------------- LN+ReLU over 512 channels (bf16 in/out) ----------------
__global__ __launch_bounds__(256) void k_ln512(const u16* __restrict__ raw,
                                               const float* __restrict__ gam,
                                               const float* __restrict__ bet,
                                               u16* __restrict__ out, int N) {
  int n = blockIdx.x * 4 + (threadIdx.x >> 6);
  int lane = threadIdx.x & 63;
  if (n >= N) return;
  const uint4* r = (const uint4*)(raw + (size_t)n * 512);
  uint4 q = r[lane];
  float v[8];
  v[0] = blo(q.x); v[1] = bhi(q.x); v[2] = blo(q.y); v[3] = bhi(q.y);
  v[4] = blo(q.z); v[5] = bhi(q.z); v[6] = blo(q.w); v[7] = bhi(q.w);
  float s1 = 0.f, s2 = 0.f;
  #pragma unroll
  for (int j = 0; j < 8; j++) { s1 += v[j]; s2 += v[j] * v[j]; }
  #pragma unroll
  for (int off = 32; off; off >>= 1) {
    s1 += __shfl_xor(s1, off);
    s2 += __shfl_xor(s2, off);
  }
  float mean = s1 * (1.f / 512.f);
  float var = s2 * (1.f / 512.f) - mean * mean;
  float rs = rsqrtf(var + 1e-5f);
  u32 o[4];
  #pragma unroll
  for (int j = 0; j < 4; j++) {
    int ch = lane * 8 + 2 * j;
    float y0 = fmaxf((v[2 * j] - mean) * rs * gam[ch] + bet[ch], 0.f);
    float y1 = fmaxf((v[2 * j + 1] - mean) * rs * gam[ch + 1] + bet[ch + 1], 0.f);
    o[j] = (u32)f2b(y0) | ((u32)f2b(y1) << 16);
  }
  ((uint4*)(out + (size_t)n * 512))[lane] = make_uint4(o[0], o[1], o[2], o[3]);
}

// ---------------- bf16 MFMA GEMM (conv2): C[M][128] = A[M][512] * Bt[128][512]^T ----------------
__global__ __launch_bounds__(256) void k_gemm_bf16(
    const u16* __restrict__ A, const u16* __restrict__ Bt,
    u16* __restrict__ C, int M, int Nc, int K) {
  __shared__ u16 As[128 * 64];
  __shared__ u16 Bs[128 * 64];
  int t = threadIdx.x;
  int lane = t & 63, wid = t >> 6;
  int wr = wid >> 1, wc = wid & 1;
  int r0 = blockIdx.x * 128, c0 = blockIdx.y * 128;
  int lr = lane & 15, lk = lane >> 4;
  f32x4 acc[4][4] = {};
  for (int kt = 0; kt < K; kt += 64) {
    #pragma unroll
    for (int it = 0; it < 4; it++) {
      int q = wid * 4096 + it * 1024 + lane * 16;
      int row = q >> 7;
      int soff = ((q >> 4) & 7) ^ (row & 7);
      {
        int gr = r0 + row; if (gr >= M) gr = M - 1;
        const u16* gp = A + (size_t)gr * K + kt + soff * 8;
        __builtin_amdgcn_global_load_lds(
            (const __attribute__((address_space(1))) void*)gp,
            (__attribute__((address_space(3))) void*)((char*)As + wid * 4096 + it * 1024),
            16, 0, 0);
      }
      {
        int gn = c0 + row;
        const u16* gp = Bt + (size_t)gn * K + kt + soff * 8;
        __builtin_amdgcn_global_load_lds(
            (const __attribute__((address_space(1))) void*)gp,
            (__attribute__((address_space(3))) void*)((char*)Bs + wid * 4096 + it * 1024),
            16, 0, 0);
      }
    }
    __syncthreads();
    const char* Ab = (const char*)As;
    const char* Bb = (const char*)Bs;
    #pragma unroll
    for (int kk = 0; kk < 2; kk++) {
      short8 a[4], b[4];
      #pragma unroll
      for (int m = 0; m < 4; m++) {
        int row = wr * 64 + m * 16 + lr;
        int off = (row << 7) + kk * 64 + lk * 16;
        off ^= (row & 7) << 4;
        a[m] = *(const short8*)(Ab + off);
      }
      #pragma unroll
      for (int nn = 0; nn < 4; nn++) {
        int row = wc * 64 + nn * 16 + lr;
        int off = (row << 7) + kk * 64 + lk * 16;
        off ^= (row & 7) << 4;
        b[nn] = *(const short8*)(Bb + off);
      }
      #pragma unroll
      for (int m = 0; m < 4; m++)
        #pragma unroll
        for (int nn = 0; nn < 4; nn++)
          acc[m][nn] = __builtin_amdgcn_mfma_f32_16x16x32_bf16(a[m], b[nn], acc[m][nn], 0, 0, 0);
    }
    __syncthreads();
  }
  #pragma unroll
  for (int m = 0; m < 4; m++)
    #pragma unroll
    for (int nn = 0; nn < 4; nn++)
      #pragma unroll
      for (int r = 0; r < 4; r++) {
        int row = r0 + wr * 64 + m * 16 + lk * 4 + r;
        if (row < M) {
          int col = c0 + wc * 64 + nn * 16 + lr;
          C[(size_t)row * Nc + col] = f2b(acc[m][nn][r]);
        }
      }
}

// ---------------- conv2 scores ----------------
__global__ void k_att_h1(const u16* __restrict__ hm, const float* __restrict__ att_s,
                         const float* __restrict__ att_d, float* __restrict__ s_out,
                         float* __restrict__ d_out, int N) {
  int n = blockIdx.x * (blockDim.x >> 6) + (threadIdx.x >> 6);
  int lane = threadIdx.x & 63;
  if (n >= N) return;
  const u32* row = (const u32*)(hm + (size_t)n * CH);
  u32 d = row[lane];
  float x0 = blo(d), x1 = bhi(d);
  float ps = x0 * att_s[2 * lane] + x1 * att_s[2 * lane + 1];
  float pd = x0 * att_d[2 * lane] + x1 * att_d[2 * lane + 1];
  #pragma unroll
  for (int off = 32; off; off >>= 1) {
    ps += __shfl_xor(ps, off);
    pd += __shfl_xor(pd, off);
  }
  if (lane == 0) { s_out[n] = ps; d_out[n] = pd; }
}

// ---------------- conv2 aggregation + bias + LN + ReLU -> h2 (fp32), no atomics ----------------
// Two nodes per wave; readlane broadcasts; pk_fma; tail-split.
__global__ __launch_bounds__(256) void k_agg2f(
    const u32* __restrict__ raw2, const int* __restrict__ indptr,
    const int* __restrict__ srcs, const float* __restrict__ as2,
    const float* __restrict__ ad2, const float* __restrict__ bias,
    const float* __restrict__ gam, const float* __restrict__ bet,
    float* __restrict__ h2, int N) {
  int t = threadIdx.x;
  int lane = t & 63, wid = t >> 6;
  int n0 = blockIdx.x * 8 + wid * 2;
  if (n0 >= N) return;
  int n1 = n0 + 1;
  bool has1 = n1 < N;
  int beg0 = indptr[n0], end0 = indptr[n0 + 1];
  int beg1 = end0, end1 = has1 ? indptr[n1 + 1] : end0;
  int deg0 = end0 - beg0, deg1 = end1 - beg1;
  float adv0 = ad2[n0];
  float adv1 = has1 ? ad2[n1] : 0.f;
  float ds0 = 0.f, ds1 = 0.f;
  f32x2 acc0 = {0.f, 0.f}, acc1 = {0.f, 0.f};

  if (deg0 <= 64 && deg1 <= 64) {
    int s0 = 0, s1r = 0;
    float w0 = 0.f, w1 = 0.f;
    if (lane < deg0) { s0 = srcs[beg0 + lane]; w0 = __expf(lrelu(as2[s0] + adv0)); }
    if (lane < deg1) { s1r = srcs[beg1 + lane]; w1 = __expf(lrelu(as2[s1r] + adv1)); }
    int dboth = (deg0 < deg1 ? deg0 : deg1) & ~7;
    int j = 0;
    for (; j < dboth; j += 8) {
      u32 d[8], e[8];
      #pragma unroll
      for (int u = 0; u < 8; u++) d[u] = raw2[(size_t)rdl(s0, j + u) * 64 + lane];
      #pragma unroll
      for (int u = 0; u < 8; u++) e[u] = raw2[(size_t)rdl(s1r, j + u) * 64 + lane];
      #pragma unroll
      for (int u = 0; u < 8; u++) {
        acc0 += bunpack(d[u]) * rdlf(w0, j + u);
        acc1 += bunpack(e[u]) * rdlf(w1, j + u);
      }
    }
    int pad0 = (deg0 + 3) & ~3;
    for (int ja = j; ja < pad0; ja += 4) {
      u32 d[4];
      #pragma unroll
      for (int u = 0; u < 4; u++) d[u] = raw2[(size_t)rdl(s0, ja + u) * 64 + lane];
      #pragma unroll
      for (int u = 0; u < 4; u++) acc0 += bunpack(d[u]) * rdlf(w0, ja + u);
    }
    int pad1 = (deg1 + 3) & ~3;
    for (int jb = j; jb < pad1; jb += 4) {
      u32 e[4];
      #pragma unroll
      for (int u = 0; u < 4; u++) e[u] = raw2[(size_t)rdl(s1r, jb + u) * 64 + lane];
      #pragma unroll
      for (int u = 0; u < 4; u++) acc1 += bunpack(e[u]) * rdlf(w1, jb + u);
    }
    // denominators via butterflies
    float v0 = w0, v1 = w1;
    #pragma unroll
    for (int off = 32; off; off >>= 1) {
      v0 += __shfl_xor(v0, off);
      v1 += __shfl_xor(v1, off);
    }
    ds0 = v0; ds1 = v1;
  } else {
    // slow path: chunked, node0 then node1
    for (int pass = 0; pass < 2; pass++) {
      if (pass == 1 && !has1) break;
      int beg = pass ? beg1 : beg0;
      int end = pass ? end1 : end0;
      float adv = pass ? adv1 : adv0;
      for (int base = beg; base < end; base += 64) {
        int cnt = min(64, end - base);
        int sreg = 0;
        float w = 0.f;
        if (lane < cnt) { sreg = srcs[base + lane]; w = __expf(lrelu(as2[sreg] + adv)); }
        int cpad = (cnt + 3) & ~3;
        for (int j = 0; j < cpad; j += 4) {
          u32 dA = raw2[(size_t)rdl(sreg, j) * 64 + lane];
          u32 dB = raw2[(size_t)rdl(sreg, j + 1) * 64 + lane];
          u32 dC = raw2[(size_t)rdl(sreg, j + 2) * 64 + lane];
          u32 dD = raw2[(size_t)rdl(sreg, j + 3) * 64 + lane];
          float wA = rdlf(w, j), wB = rdlf(w, j + 1);
          float wC = rdlf(w, j + 2), wD = rdlf(w, j + 3);
          f32x2 s = bunpack(dA) * wA;
          s += bunpack(dB) * wB;
          s += bunpack(dC) * wC;
          s += bunpack(dD) * wD;
          float sw = (wA + wB) + (wC + wD);
          if (pass) { ds1 += sw; acc1 += s; }
          else      { ds0 += sw; acc0 += s; }
        }
      }
    }
  }

  // LN + ReLU, both nodes (butterflies interleaved), write h2 rows
  float inv0 = 1.f / (ds0 + 1e-16f);
  float v00 = acc0.x * inv0 + bias[2 * lane];
  float v01 = acc0.y * inv0 + bias[2 * lane + 1];
  float s1a = v00 + v01, s2a = v00 * v00 + v01 * v01;
  float inv1 = 1.f / (ds1 + 1e-16f);
  float v10 = acc1.x * inv1 + bias[2 * lane];
  float v11 = acc1.y * inv1 + bias[2 * lane + 1];
  float s1b = v10 + v11, s2b = v10 * v10 + v11 * v11;
  #pragma unroll
  for (int off = 32; off; off >>= 1) {
    s1a += __shfl_xor(s1a, off);
    s2a += __shfl_xor(s2a, off);
    s1b += __shfl_xor(s1b, off);
    s2b += __shfl_xor(s2b, off);
  }
  {
    float mean = s1a * (1.f / 128.f);
    float var = s2a * (1.f / 128.f) - mean * mean;
    float rs = rsqrtf(var + 1e-5f);
    float y0 = fmaxf((v00 - mean) * rs * gam[2 * lane] + bet[2 * lane], 0.f);
    float y1 = fmaxf((v01 - mean) * rs * gam[2 * lane + 1] + bet[2 * lane + 1], 0.f);
    ((float2*)(h2 + (size_t)n0 * 128))[lane] = make_float2(y0, y1);
  }
  if (has1) {
    float mean = s1b * (1.f / 128.f);
    float var = s2b * (1.f / 128.f) - mean * mean;
    float rs = rsqrtf(var + 1e-5f);
    float y0 = fmaxf((v10 - mean) * rs * gam[2 * lane] + bet[2 * lane], 0.f);
    float y1 = fmaxf((v11 - mean) * rs * gam[2 * lane + 1] + bet[2 * lane + 1], 0.f);
    ((float2*)(h2 + (size_t)n1 * 128))[lane] = make_float2(y0, y1);
  }
}

// ---------------- MLP head with segment-sum pooling (batch is sorted; no atomics) ----------------
__global__ __launch_bounds__(256) void k_head(const float* __restrict__ h2,
    const int* __restrict__ batch, int N,
    const float* __restrict__ rW1, const float* __restrict__ rb1,
    const float* __restrict__ rg, const float* __restrict__ rbe,
    const float* __restrict__ rW2, const float* __restrict__ rb2,
    float* __restrict__ outp) {
  int g = blockIdx.x, t = threadIdx.x;
  int ch = t & 127, half = t >> 7;
  __shared__ float part[2][128];
  __shared__ float pl[128];
  __shared__ float yv[32];
  __shared__ float rv[32];
  __shared__ float mv[2];
  __shared__ int sseg[2];
  if (t == 0) {
    int lo = 0, hi = N;
    while (lo < hi) { int mid = (lo + hi) >> 1; if (batch[mid] < g) lo = mid + 1; else hi = mid; }
    int lo2 = lo, hi2 = N;
    while (lo2 < hi2) { int mid = (lo2 + hi2) >> 1; if (batch[mid] < g + 1) lo2 = mid + 1; else hi2 = mid; }
    sseg[0] = lo; sseg[1] = lo2;
  }
  __syncthreads();
  int lo = sseg[0], hi = sseg[1];
  float s = 0.f;
  int n = lo + half;
  for (; n + 8 <= hi; n += 8) {
    s += h2[(size_t)n * 128 + ch] + h2[(size_t)(n + 2) * 128 + ch]
       + h2[(size_t)(n + 4) * 128 + ch] + h2[(size_t)(n + 6) * 128 + ch];
  }
  for (; n < hi; n += 2) s += h2[(size_t)n * 128 + ch];
  part[half][ch] = s;
  __syncthreads();
  float cnt = fmaxf((float)(hi - lo), 1.f);
  if (t < 128) pl[t] = (part[0][t] + part[1][t]) / cnt;
  __syncthreads();
  if (t < 32) {
    float sum = rb1[t];
    for (int c = 0; c < 128; c++) sum += pl[c] * rW1[c * 32 + t];
    yv[t] = sum;
  }
  __syncthreads();
  if (t == 0) {
    float sm = 0.f, sq = 0.f;
    for (int j = 0; j < 32; j++) { sm += yv[j]; sq += yv[j] * yv[j]; }
    float mean = sm / 32.f;
    float var = sq / 32.f - mean * mean;
    mv[0] = mean; mv[1] = rsqrtf(var + 1e-5f);
  }
  __syncthreads();
  if (t < 32) {
    float y = (yv[t] - mv[0]) * mv[1] * rg[t] + rbe[t];
    rv[t] = fmaxf(y, 0.f);
  }
  __syncthreads();
  if (t < OUT_DIM) {
    float sum = rb2[t];
    for (int j = 0; j < 32; j++) sum += rv[j] * rW2[j * 8 + t];
    outp[g * 8 + t] = sum;
  }
}

extern "C" void kernel_launch(void* const* d_in, const int* in_sizes, int n_in,
                              void* d_out, int out_size, void* d_ws, size_t ws_size,
                              hipStream_t stream) {
  const float* x    = (const float*)d_in[0];
  const int*   ei   = (const int*)d_in[1];
  const int*   batch= (const int*)d_in[3];
  const float* W1   = (const float*)d_in[4];
  const float* as1w = (const float*)d_in[5];
  const float* ad1w = (const float*)d_in[6];
  const float* b1   = (const float*)d_in[7];
  const float* g1   = (const float*)d_in[8];
  const float* be1  = (const float*)d_in[9];
  const float* W2   = (const float*)d_in[10];
  const float* as2w = (const float*)d_in[11];
  const float* ad2w = (const float*)d_in[12];
  const float* b2   = (const float*)d_in[13];
  const float* g2   = (const float*)d_in[14];
  const float* be2  = (const float*)d_in[15];
  const float* rW1  = (const float*)d_in[16];
  const float* rb1  = (const float*)d_in[17];
  const float* rg   = (const float*)d_in[18];
  const float* rbe  = (const float*)d_in[19];
  const float* rW2  = (const float*)d_in[20];
  const float* rb2  = (const float*)d_in[21];

  int N = in_sizes[0] / 128;
  int E = in_sizes[1] / 2;
  int ET = E + N;
  int nb = (N + 255) / 256;

  char* p = (char*)d_ws;
  u16* x_b   = (u16*)p; p += (size_t)N * 128 * 2;
  u16* aggx  = (u16*)p; p += (size_t)N * 512 * 2;
  u16* raw1  = (u16*)p; p += (size_t)N * 512 * 2;
  u16* h1_b  = (u16*)p; p += (size_t)N * 512 * 2;
  u16* raw2b = (u16*)p; p += (size_t)N * 128 * 2;
  float* h2  = (float*)p; p += (size_t)N * 128 * 4;
  u16* W1t   = (u16*)p; p += 512 * 128 * 2;
  u16* W2t   = (u16*)p; p += 128 * 512 * 2;
  u16* wst   = (u16*)p; p += 16 * 128 * 2;
  float* sa1 = (float*)p; p += (size_t)N * 4 * 4;
  float* da1 = (float*)p; p += (size_t)N * 4 * 4;
  float* sa2 = (float*)p; p += (size_t)N * 4;
  float* da2 = (float*)p; p += (size_t)N * 4;
  int* counts = (int*)p; p += (size_t)N * 4;
  int* indptr = (int*)p; p += (size_t)(N + 1) * 4;
  int* cursor = (int*)p; p += (size_t)N * 4;
  int* bsum   = (int*)p; p += (size_t)nb * 4;
  int* boff   = (int*)p; p += (size_t)nb * 4;
  int* srcs   = (int*)p; p += (size_t)ET * 4;

  hipMemsetAsync(counts, 0, (size_t)N * sizeof(int), stream);

  int eb = (ET + 255) / 256;

  // weight prep (one kernel): W1t, W2t, wst
  k_wprep<<<513, 256, 0, stream>>>(W1, W2, as1w, ad1w, W1t, W2t, wst);

  // edge counting + x->bf16 conversion (one kernel, flat streaming)
  int cb = (N * 32 + 255) / 256;
  k_count_prep<<<eb + cb, 256, 0, stream>>>(ei, counts, E, N, eb, x, (uint2*)x_b);

  // conv1 scores via MFMA (xb is L2/L3-hot)
  k_score<<<(N + 255) / 256, 256, 0, stream>>>(x_b, wst, sa1, da1, N);

  k_scanA<<<nb, 256, 0, stream>>>(counts, bsum, N);
  k_scanB<<<1, 1024, 0, stream>>>(bsum, boff, nb);
  k_scanC<<<nb, 256, 0, stream>>>(counts, boff, indptr, cursor, N);
  k_scatter<<<eb, 256, 0, stream>>>(ei, cursor, srcs, E, N);

  // conv1: aggregate x (2 nodes per wave), per-head GEMM (+bias), LN+ReLU
  k_aggx<<<(N + 7) / 8, 256, 0, stream>>>((const u32*)x_b, indptr, srcs,
                                          (const float4*)sa1, (const float4*)da1,
                                          (u32*)aggx, N);
  dim3 gridh((N + 127) / 128, 4);
  k_gemm_head<<<gridh, 256, 0, stream>>>(aggx, W1t, b1, raw1, N);
  k_ln512<<<(N + 3) / 4, 256, 0, stream>>>(raw1, g1, be1, h1_b, N);

  // conv2
  dim3 grid2((N + 127) / 128, 1);
  k_gemm_bf16<<<grid2, 256, 0, stream>>>(h1_b, W2t, raw2b, N, 128, 512);
  k_att_h1<<<(N + 3) / 4, 256, 0, stream>>>(raw2b, as2w, ad2w, sa2, da2, N);
  k_agg2f<<<(N + 7) / 8, 256, 0, stream>>>((const u32*)raw2b, indptr, srcs, sa2, da2,
                                           b2, g2, be2, h2, N);

  // head: segment-sum pooling (batch sorted) + MLP
  k_head<<<GRAPHS, 256, 0, stream>>>(h2, batch, N, rW1, rb1, rg, rbe, rW2, rb2,
                                     (float*)d_out);
}